// Round 7
// baseline (503.812 us; speedup 1.0000x reference)
//
#include <hip/hip_runtime.h>

using short8  = __attribute__((ext_vector_type(8))) short;
using floatx4 = __attribute__((ext_vector_type(4))) float;

// ---------- bf16 helpers ----------
static __device__ __forceinline__ float bf2f(unsigned short u) {
    union { unsigned u; float f; } v; v.u = ((unsigned)u) << 16; return v.f;
}
static __device__ __forceinline__ unsigned short f2bf(float f) {
    union { float f; unsigned u; } v; v.f = f;
    unsigned r = v.u + 0x7FFFu + ((v.u >> 16) & 1u);   // round-to-nearest-even
    return (unsigned short)(r >> 16);
}

// ---------- fused: degree histogram + all weight transposes (independent work) ----------
__global__ void histw_kernel(const int* __restrict__ dst, int* __restrict__ cnt, int E,
                             const float* __restrict__ Win, const float* __restrict__ Wg,
                             const float* __restrict__ Wout,
                             unsigned short* __restrict__ WinT, unsigned short* __restrict__ WgT,
                             unsigned short* __restrict__ WoutT) {
    int HB = (E + 255) >> 8;
    int b = blockIdx.x;
    if (b < HB) {
        int i = b * 256 + threadIdx.x;
        if (i < E) atomicAdd(&cnt[dst[i]], 1);
    } else {
        int i = (b - HB) * 256 + threadIdx.x;
        if (i < 16384) {                       // Win 128x128
            int m = i & 127, k = i >> 7;
            WinT[m * 128 + k] = f2bf(Win[i]);
        } else if (i < 81920) {                // Wg 4x128x128
            int j = i - 16384;
            int m = j & 127, k = (j >> 7) & 127, mat = j >> 14;
            WgT[mat * 16384 + m * 128 + k] = f2bf(Wg[j]);
        } else if (i < 90112) {                // Wout 128x64
            int j = i - 81920;
            int m = j % 64, k = j / 64;
            WoutT[m * 128 + k] = f2bf(Wout[j]);
        }
    }
}

// ---------- single-kernel exclusive scan over cnt[0..n), nb <= 256 blocks ----------
__global__ __launch_bounds__(256) void scanall_kernel(const int* __restrict__ cnt,
        unsigned* __restrict__ bsum, unsigned* __restrict__ boff, unsigned* __restrict__ done,
        int* __restrict__ rowptr,
        float* __restrict__ dis, float* __restrict__ selfn, int n, int nb) {
    __shared__ int s[256];
    __shared__ int s2[256];
    __shared__ int flag_agg;
    __shared__ int blkoff;
    const int b = blockIdx.x, tid = threadIdx.x;
    int i = b * 256 + tid;
    int cc = (i < n) ? cnt[i] : 0;
    s[tid] = cc;
    __syncthreads();
    for (int off = 1; off < 256; off <<= 1) {   // inclusive scan in LDS
        int t = s[tid];
        int a = (tid >= off) ? s[tid - off] : 0;
        __syncthreads();
        s[tid] = t + a;
        __syncthreads();
    }
    if (tid == 0) {
        atomicExch(&bsum[b], (unsigned)s[255] | 0x80000000u);   // publish block total
        __threadfence();                                        // release
        unsigned t = atomicAdd(done, 1u);
        flag_agg = (t == (unsigned)(nb - 1)) ? 1 : 0;           // last arrival aggregates
    }
    __syncthreads();
    if (flag_agg) {
        __threadfence();                                        // acquire
        unsigned val = (tid < nb) ? (atomicOr(&bsum[tid], 0u) & 0x7fffffffu) : 0u;
        s2[tid] = (int)val;
        __syncthreads();
        for (int off = 1; off < 256; off <<= 1) {
            int t = s2[tid];
            int a = (tid >= off) ? s2[tid - off] : 0;
            __syncthreads();
            s2[tid] = t + a;
            __syncthreads();
        }
        if (tid < nb)
            atomicExch(&boff[tid], ((unsigned)s2[tid] - val) | 0x80000000u); // exclusive
    }
    if (tid == 0) {
        unsigned vv;
        while (((vv = atomicOr(&boff[b], 0u)) & 0x80000000u) == 0u)
            __builtin_amdgcn_s_sleep(8);
        blkoff = (int)(vv & 0x7fffffffu);
    }
    __syncthreads();
    if (i < n) {
        int pre = blkoff + s[tid] - cc;       // exclusive prefix
        rowptr[i] = pre;
        float d = (float)cc + 1.0f;           // deg = in-degree + self-loop
        dis[i] = rsqrtf(d);
        selfn[i] = 1.0f / d;
        if (i == n - 1) rowptr[n] = pre + cc;
    }
}

// ---------- merged: mgemm2 (blocks [0,GB)) + bucket phase-1 (blocks [GB, GB+FB)) ----------
// Phase 1 appends 4B records {src:16, dstLow:8} to bucket dst>>8, sub-segment k&7
// (XCD-affine tail lines, fully-filled before eviction -> ~2.4MB writes, no RMW thrash).
__global__ __launch_bounds__(256) void fillgemm_kernel(
        const float* __restrict__ X,
        const unsigned short* __restrict__ W1T, const float* __restrict__ b1,
        const unsigned short* __restrict__ W2T,
        unsigned short* __restrict__ H0, unsigned short* __restrict__ T0, int nrows, int GB,
        const int* __restrict__ src, const int* __restrict__ dst,
        int* __restrict__ cursor8, unsigned* __restrict__ stage, int E) {
    __shared__ unsigned short Al[64 * 136];
    __shared__ unsigned short Wl[128 * 136];
    const int tid = threadIdx.x;

    if (blockIdx.x >= GB) {
        // ---------------- bucket phase-1 branch ----------------
        int k = blockIdx.x - GB;
        int i = k * 256 + tid;
        if (i < E) {
            int s = src[i], d = dst[i];
            int bk = (d >> 8) * 8 + (k & 7);
            int idx = atomicAdd(&cursor8[bk], 1);
            if (idx > 1023) idx = 1023;                 // statistically unreachable
            unsigned rec = (unsigned)s | ((unsigned)(d & 255) << 16);
            __builtin_nontemporal_store(rec, &stage[(unsigned)bk * 1024 + idx]);
        }
        return;
    }

    // ---------------- mgemm2 branch ----------------
    const int w     = tid >> 6;
    const int lane  = tid & 63;
    const int col_l = lane & 15;
    const int quad  = lane >> 4;
    const int row_base = blockIdx.x * 64;

#pragma unroll
    for (int it = 0; it < 8; ++it) {
        int idx = it * 256 + tid;
        int r = idx >> 5, c4 = idx & 31;
        int gr = row_base + r; if (gr >= nrows) gr = nrows - 1;
        float4 v = *(const float4*)&X[(size_t)gr * 128 + c4 * 4];
        ushort4 u;
        u.x = f2bf(v.x); u.y = f2bf(v.y); u.z = f2bf(v.z); u.w = f2bf(v.w);
        *(ushort4*)&Al[r * 136 + c4 * 4] = u;
    }
#pragma unroll
    for (int it = 0; it < 8; ++it) {
        int idx = it * 256 + tid;
        int r = idx >> 4, ch = idx & 15;
        *(float4*)&Wl[r * 136 + ch * 8] = *(const float4*)&W1T[(size_t)r * 128 + ch * 8];
    }
    __syncthreads();

    short8 af[4];
    const int arow = w * 16 + col_l;
#pragma unroll
    for (int ks = 0; ks < 4; ++ks)
        af[ks] = *(const short8*)&Al[arow * 136 + ks * 32 + quad * 8];

    floatx4 acc[8];
#pragma unroll
    for (int ct = 0; ct < 8; ++ct) {
        acc[ct] = (floatx4){0.f, 0.f, 0.f, 0.f};
#pragma unroll
        for (int ks = 0; ks < 4; ++ks) {
            short8 bf = *(const short8*)&Wl[(ct * 16 + col_l) * 136 + ks * 32 + quad * 8];
            acc[ct] = __builtin_amdgcn_mfma_f32_16x16x32_bf16(af[ks], bf, acc[ct], 0, 0, 0);
        }
    }
    __syncthreads();   // all LDS reads done before overwrite

#pragma unroll
    for (int ct = 0; ct < 8; ++ct) {
        int col = ct * 16 + col_l;
        float bv = b1[col];
#pragma unroll
        for (int r = 0; r < 4; ++r) {
            int row_l = w * 16 + quad * 4 + r;
            float o = acc[ct][r] + bv;
            unsigned short ob = f2bf(o);
            Al[row_l * 136 + col] = ob;
            int gr = row_base + row_l;
            if (gr < nrows) H0[(size_t)gr * 128 + col] = ob;
        }
    }
#pragma unroll
    for (int it = 0; it < 8; ++it) {
        int idx = it * 256 + tid;
        int r = idx >> 4, ch = idx & 15;
        *(float4*)&Wl[r * 136 + ch * 8] = *(const float4*)&W2T[(size_t)r * 128 + ch * 8];
    }
    __syncthreads();

#pragma unroll
    for (int ks = 0; ks < 4; ++ks)
        af[ks] = *(const short8*)&Al[arow * 136 + ks * 32 + quad * 8];
#pragma unroll
    for (int ct = 0; ct < 8; ++ct) {
        acc[ct] = (floatx4){0.f, 0.f, 0.f, 0.f};
#pragma unroll
        for (int ks = 0; ks < 4; ++ks) {
            short8 bf = *(const short8*)&Wl[(ct * 16 + col_l) * 136 + ks * 32 + quad * 8];
            acc[ct] = __builtin_amdgcn_mfma_f32_16x16x32_bf16(af[ks], bf, acc[ct], 0, 0, 0);
        }
    }
#pragma unroll
    for (int ct = 0; ct < 8; ++ct) {
        int col = ct * 16 + col_l;
#pragma unroll
        for (int r = 0; r < 4; ++r) {
            int gr = row_base + w * 16 + quad * 4 + r;
            if (gr < nrows) T0[(size_t)gr * 128 + col] = f2bf(acc[ct][r]);
        }
    }
}

// ---------- bucket phase-2: place records at CSR slots via LDS node cursors ----------
// Block b: nodes [256b, 256b+256). Reads its 8 sub-segments sequentially; scattered
// epack writes land in a ~24KB window (L2-hot, lines fully filled).
__global__ __launch_bounds__(256) void scatter_kernel(
        const unsigned* __restrict__ stage, const int* __restrict__ cursor8,
        const int* __restrict__ rowptr, const float* __restrict__ dis,
        unsigned long long* __restrict__ epack, int n) {
    __shared__ int   curs[256];
    __shared__ float disn[256];
    const int b = blockIdx.x, tid = threadIdx.x;
    int node = b * 256 + tid;
    if (node < n) { curs[tid] = rowptr[node]; disn[tid] = dis[node]; }
    else          { curs[tid] = 0;            disn[tid] = 0.f; }
    __syncthreads();
#pragma unroll 1
    for (int s = 0; s < 8; ++s) {
        int bk  = b * 8 + s;
        int cnt = cursor8[bk]; if (cnt > 1024) cnt = 1024;
        const unsigned* sg = stage + (unsigned)bk * 1024;
        for (int i = tid; i < cnt; i += 256) {
            unsigned rec = sg[i];
            int sc = rec & 0xFFFF;
            int dl = (rec >> 16) & 255;
            int slot = atomicAdd(&curs[dl], 1);
            float w = dis[sc] * disn[dl];
            unsigned long long r2 = (unsigned long long)(unsigned)sc |
                                    ((unsigned long long)__float_as_uint(w) << 32);
            epack[slot] = r2;
        }
    }
}

// ---------- fused BN(+skip+relu+ACC[bf16]) -> MFMA GEMM (AGG bf16) ----------
// stats come as 8 shards of 256 floats (sum[128], sumsq[128]); summed here.
template<int MO, bool STAGE_ACC, bool OB16>
__global__ __launch_bounds__(256) void mgemm_bn_kernel(
        const unsigned short* __restrict__ AGGB, const float* __restrict__ stats,
        const float* __restrict__ gamma, const float* __restrict__ beta,
        const unsigned short* __restrict__ XSKIP, unsigned short* __restrict__ ACC,
        const unsigned short* __restrict__ WT, const float* __restrict__ bias,
        void* __restrict__ C, int nrows, float inv_n, int do_skip, int first) {
    constexpr int NT = MO / 16;
    __shared__ unsigned short Al[64 * 136];
    __shared__ unsigned short Wl[MO * 136];
    __shared__ float ABl[256];
    const int tid   = threadIdx.x;
    const int w     = tid >> 6;
    const int lane  = tid & 63;
    const int col_l = lane & 15;
    const int quad  = lane >> 4;
    const int row_base = blockIdx.x * 64;

    if (tid < 128) {
        float s = 0.f, ss = 0.f;
#pragma unroll
        for (int k = 0; k < 8; ++k) {
            s  += stats[k * 256 + tid];
            ss += stats[k * 256 + 128 + tid];
        }
        float m = s * inv_n;
        float var = ss * inv_n - m * m;
        float inv = rsqrtf(var + 1e-5f);
        float Ax = inv * gamma[tid];
        ABl[tid] = Ax;
        ABl[128 + tid] = beta[tid] - m * Ax;
    }
#pragma unroll
    for (int it = 0; it < MO / 16; ++it) {
        int idx = it * 256 + tid;
        int r = idx >> 4, ch = idx & 15;
        *(float4*)&Wl[r * 136 + ch * 8] = *(const float4*)&WT[(size_t)r * 128 + ch * 8];
    }
    __syncthreads();

#pragma unroll
    for (int it = 0; it < 8; ++it) {
        int idx = it * 256 + tid;
        int r = idx >> 5, c4 = idx & 31;
        int gr = row_base + r;
        ushort4 hu = make_ushort4(0, 0, 0, 0);
        if (gr < nrows) {
            ushort4 xb = *(const ushort4*)&AGGB[(size_t)gr * 128 + c4 * 4];
            float4 Av = ((const float4*)ABl)[c4];
            float4 Bv = ((const float4*)ABl)[32 + c4];
            float4 t;
            t.x = fmaf(bf2f(xb.x), Av.x, Bv.x);
            t.y = fmaf(bf2f(xb.y), Av.y, Bv.y);
            t.z = fmaf(bf2f(xb.z), Av.z, Bv.z);
            t.w = fmaf(bf2f(xb.w), Av.w, Bv.w);
            if (do_skip) {
                ushort4 sk = *(const ushort4*)&XSKIP[(size_t)gr * 128 + c4 * 4];
                t.x = fmaf(0.5f, bf2f(sk.x), t.x);
                t.y = fmaf(0.5f, bf2f(sk.y), t.y);
                t.z = fmaf(0.5f, bf2f(sk.z), t.z);
                t.w = fmaf(0.5f, bf2f(sk.w), t.w);
            }
            t.x = fmaxf(t.x, 0.f); t.y = fmaxf(t.y, 0.f);
            t.z = fmaxf(t.z, 0.f); t.w = fmaxf(t.w, 0.f);
            float4 a;
            if (first) {
                a = t;
            } else {
                ushort4 ab = *(const ushort4*)&ACC[(size_t)gr * 128 + c4 * 4];
                a.x = bf2f(ab.x) + t.x;
                a.y = bf2f(ab.y) + t.y;
                a.z = bf2f(ab.z) + t.z;
                a.w = bf2f(ab.w) + t.w;
            }
            float4 sv;
            if (STAGE_ACC) sv = a; else sv = t;
            hu.x = f2bf(sv.x); hu.y = f2bf(sv.y); hu.z = f2bf(sv.z); hu.w = f2bf(sv.w);
            if (!STAGE_ACC) {
                ushort4 au;
                au.x = f2bf(a.x); au.y = f2bf(a.y); au.z = f2bf(a.z); au.w = f2bf(a.w);
                *(ushort4*)&ACC[(size_t)gr * 128 + c4 * 4] = au;
            }
        }
        *(ushort4*)&Al[r * 136 + c4 * 4] = hu;
    }
    __syncthreads();

    short8 af[4];
    const int arow = w * 16 + col_l;
#pragma unroll
    for (int ks = 0; ks < 4; ++ks)
        af[ks] = *(const short8*)&Al[arow * 136 + ks * 32 + quad * 8];

    floatx4 acc[NT];
#pragma unroll
    for (int ct = 0; ct < NT; ++ct) {
        acc[ct] = (floatx4){0.f, 0.f, 0.f, 0.f};
#pragma unroll
        for (int ks = 0; ks < 4; ++ks) {
            short8 bf = *(const short8*)&Wl[(ct * 16 + col_l) * 136 + ks * 32 + quad * 8];
            acc[ct] = __builtin_amdgcn_mfma_f32_16x16x32_bf16(af[ks], bf, acc[ct], 0, 0, 0);
        }
    }

#pragma unroll
    for (int ct = 0; ct < NT; ++ct) {
        int col = ct * 16 + col_l;
        float bv = bias ? bias[col] : 0.f;
#pragma unroll
        for (int r = 0; r < 4; ++r) {
            int gr = row_base + w * 16 + quad * 4 + r;
            if (gr < nrows) {
                float o = acc[ct][r] + bv;
                if (OB16) ((unsigned short*)C)[(size_t)gr * MO + col] = f2bf(o);
                else      ((float*)C)[(size_t)gr * MO + col] = o;
            }
        }
    }
}

// ---------- persistent CSR gather aggregation + fused BN stats ----------
__global__ __launch_bounds__(256) void aggstat_kernel(const unsigned short* __restrict__ T,
        const int* __restrict__ rowptr, const unsigned long long* __restrict__ epack,
        const float* __restrict__ selfn,
        unsigned short* __restrict__ AGGB, float* __restrict__ stats, int n, int nw) {
    const int w    = threadIdx.x >> 6;
    const int lane = threadIdx.x & 63;
    const int wid  = blockIdx.x * 4 + w;
    const int c    = lane * 2;
    float s1x = 0.f, s1y = 0.f, s2x = 0.f, s2y = 0.f;

    for (int v = wid; v < n; v += nw) {
        ushort2 tv = *(const ushort2*)&T[(size_t)v * 128 + c];
        float sn = selfn[v];
        float ax = bf2f(tv.x) * sn, ay = bf2f(tv.y) * sn;
        int e = rowptr[v], e1 = rowptr[v + 1];
        for (; e + 8 <= e1; e += 8) {
            unsigned long long d[8]; ushort2 t[8];
#pragma unroll
            for (int j = 0; j < 8; ++j) d[j] = __builtin_nontemporal_load(&epack[e + j]);
#pragma unroll
            for (int j = 0; j < 8; ++j)
                t[j] = *(const ushort2*)&T[(size_t)(unsigned)d[j] * 128 + c];
#pragma unroll
            for (int j = 0; j < 8; ++j) {
                float wj = __uint_as_float((unsigned)(d[j] >> 32));
                ax = fmaf(wj, bf2f(t[j].x), ax);
                ay = fmaf(wj, bf2f(t[j].y), ay);
            }
        }
        for (; e + 4 <= e1; e += 4) {
            unsigned long long d[4]; ushort2 t[4];
#pragma unroll
            for (int j = 0; j < 4; ++j) d[j] = __builtin_nontemporal_load(&epack[e + j]);
#pragma unroll
            for (int j = 0; j < 4; ++j)
                t[j] = *(const ushort2*)&T[(size_t)(unsigned)d[j] * 128 + c];
#pragma unroll
            for (int j = 0; j < 4; ++j) {
                float wj = __uint_as_float((unsigned)(d[j] >> 32));
                ax = fmaf(wj, bf2f(t[j].x), ax);
                ay = fmaf(wj, bf2f(t[j].y), ay);
            }
        }
        for (; e < e1; ++e) {
            unsigned long long d0 = __builtin_nontemporal_load(&epack[e]);
            ushort2 tu = *(const ushort2*)&T[(size_t)(unsigned)d0 * 128 + c];
            float w0 = __uint_as_float((unsigned)(d0 >> 32));
            ax = fmaf(w0, bf2f(tu.x), ax);
            ay = fmaf(w0, bf2f(tu.y), ay);
        }
        ushort2 o; o.x = f2bf(ax); o.y = f2bf(ay);
        *(ushort2*)&AGGB[(size_t)v * 128 + c] = o;
        float rx = bf2f(o.x), ry = bf2f(o.y);   // stats on bf16-rounded values
        s1x += rx; s1y += ry;
        s2x = fmaf(rx, rx, s2x); s2y = fmaf(ry, ry, s2y);
    }

    __shared__ float r1[4][130];
    __shared__ float r2[4][130];
    r1[w][c] = s1x; r1[w][c + 1] = s1y;
    r2[w][c] = s2x; r2[w][c + 1] = s2y;
    __syncthreads();
    if (w == 0) {
        float a1 = r1[0][c] + r1[1][c] + r1[2][c] + r1[3][c];
        float b1 = r1[0][c + 1] + r1[1][c + 1] + r1[2][c + 1] + r1[3][c + 1];
        float a2 = r2[0][c] + r2[1][c] + r2[2][c] + r2[3][c];
        float b2 = r2[0][c + 1] + r2[1][c + 1] + r2[2][c + 1] + r2[3][c + 1];
        float* sh = stats + (blockIdx.x & 7) * 256;
        atomicAdd(&sh[c], a1);
        atomicAdd(&sh[c + 1], b1);
        atomicAdd(&sh[128 + c], a2);
        atomicAdd(&sh[128 + c + 1], b2);
    }
}

extern "C" void kernel_launch(void* const* d_in, const int* in_sizes, int n_in,
                              void* d_out, int out_size, void* d_ws, size_t ws_size,
                              hipStream_t stream) {
    (void)n_in; (void)out_size; (void)ws_size;
    const float* x    = (const float*)d_in[0];
    const float* Win  = (const float*)d_in[1];
    const float* bin  = (const float*)d_in[2];
    const float* Wg   = (const float*)d_in[3];
    // d_in[4] = b_g: cancelled by BN mean-subtract, unused.
    const float* gamma = (const float*)d_in[5];
    const float* beta  = (const float*)d_in[6];
    const float* Wout  = (const float*)d_in[7];
    const float* bout  = (const float*)d_in[8];
    const int*   eidx  = (const int*)d_in[9];
    float* out = (float*)d_out;

    const int N = in_sizes[0] / 128;   // 50000 nodes
    const int E = in_sizes[9] / 2;     // 600000 edges
    const int* esrc_in = eidx;
    const int* edst_in = eidx + E;

    char* p = (char*)d_ws;
    auto alloc = [&](size_t bytes) { char* r = p; p += (bytes + 255) & ~(size_t)255; return r; };
    const size_t NB2 = (size_t)N * 128 * sizeof(unsigned short);
    unsigned short* h0b   = (unsigned short*)alloc(NB2);  // x_skip (bf16)
    unsigned short* tb16  = (unsigned short*)alloc(NB2);  // t (bf16)
    unsigned short* aggb  = (unsigned short*)alloc(NB2);  // agg (bf16)
    unsigned short* accb  = (unsigned short*)alloc(NB2);  // ACC (bf16)
    unsigned short* WinT  = (unsigned short*)alloc(128 * 128 * 2);
    unsigned short* WgT   = (unsigned short*)alloc(4 * 128 * 128 * 2);
    unsigned short* WoutT = (unsigned short*)alloc(128 * 64 * 2);
    float* disb  = (float*)alloc((size_t)N * 4);
    float* selfn = (float*)alloc((size_t)N * 4);

    const int NBUK = (N + 255) / 256;  // 196 buckets of 256 nodes
    // ---- contiguous zero region: cnt | bsum | boff | done | stats4 | cursor8 ----
    char* z0 = p;
    int*      cnt    = (int*)alloc((size_t)N * 4);
    unsigned* bsum   = (unsigned*)alloc(256 * 4);
    unsigned* boff   = (unsigned*)alloc(256 * 4);
    unsigned* done   = (unsigned*)alloc(256);
    float*    stats4 = (float*)alloc((size_t)4 * 8 * 256 * 4);   // [layer][shard 0..7][256]
    int*      cursor8 = (int*)alloc((size_t)NBUK * 8 * 4);       // per (bucket,sub) cursor
    const size_t zbytes = (size_t)(p - z0);
    int*      rowptr = (int*)alloc((size_t)(N + 1) * 4);
    unsigned* stage  = (unsigned*)alloc((size_t)NBUK * 8 * 1024 * 4);  // 6.4MB staging
    unsigned long long* epack = (unsigned long long*)alloc((size_t)E * 8);

    auto cdiv = [](int a, int b) { return (a + b - 1) / b; };
    const int NBLK = cdiv(N, 256);     // 196 (must be <= 256 for scanall)
    const float inv_n = 1.0f / (float)N;
    const int AGG_BLOCKS = 2048;       // 8192 waves = full residency; ~6 nodes/wave
    const int AGG_WAVES  = AGG_BLOCKS * 4;
    const int GB = cdiv(N, 64);        // mgemm2 tile blocks (782)
    const int FB = cdiv(E, 256);       // phase-1 blocks (2344)

    // graph preprocessing (+ weight transposes fused into the hist launch)
    hipMemsetAsync(z0, 0, zbytes, stream);
    histw_kernel<<<cdiv(E, 256) + 352, 256, 0, stream>>>(edst_in, cnt, E,
                                                         Win, Wg, Wout, WinT, WgT, WoutT);
    scanall_kernel<<<NBLK, 256, 0, stream>>>(cnt, bsum, boff, done, rowptr,
                                             disb, selfn, N, NBLK);

    // merged: startup GEMMs (h0 = x@W_in+b_in ; t0 = h0@Wg[0]) || bucket phase-1
    fillgemm_kernel<<<GB + FB, 256, 0, stream>>>(x, WinT, bin, WgT, h0b, tb16, N, GB,
                                                 esrc_in, edst_in, cursor8, stage, E);
    // bucket phase-2: place records into CSR epack
    scatter_kernel<<<NBUK, 256, 0, stream>>>(stage, cursor8, rowptr, disb, epack, N);

    for (int i = 0; i < 4; ++i) {
        float* stats = stats4 + (size_t)i * 8 * 256;
        aggstat_kernel<<<AGG_BLOCKS, 256, 0, stream>>>(tb16, rowptr, epack, selfn,
                                                       aggb, stats, N, AGG_WAVES);
        if (i < 3) {
            mgemm_bn_kernel<128, false, true><<<cdiv(N, 64), 256, 0, stream>>>(
                aggb, stats, gamma + i * 128, beta + i * 128, h0b, accb,
                WgT + (size_t)(i + 1) * 128 * 128, nullptr, (void*)tb16, N,
                inv_n, (i & 1), (i == 0) ? 1 : 0);
        } else {
            mgemm_bn_kernel<64, true, false><<<cdiv(N, 64), 256, 0, stream>>>(
                aggb, stats, gamma + i * 128, beta + i * 128, h0b, accb,
                WoutT, bout, (void*)out, N, inv_n, 1, 0);
        }
    }
}

// Round 8
// 418.069 us; speedup vs baseline: 1.2051x; 1.2051x over previous
//
#include <hip/hip_runtime.h>

using short8  = __attribute__((ext_vector_type(8))) short;
using floatx4 = __attribute__((ext_vector_type(4))) float;

// ---------- bf16 helpers ----------
static __device__ __forceinline__ float bf2f(unsigned short u) {
    union { unsigned u; float f; } v; v.u = ((unsigned)u) << 16; return v.f;
}
static __device__ __forceinline__ unsigned short f2bf(float f) {
    union { float f; unsigned u; } v; v.f = f;
    unsigned r = v.u + 0x7FFFu + ((v.u >> 16) & 1u);   // round-to-nearest-even
    return (unsigned short)(r >> 16);
}

// ---------- fused: weight transposes + degree histogram + exclusive scan ----------
// nb blocks (<=256), all co-resident. Device-scope barrier on done[0] between the
// histogram and the scan (cross-XCD visibility via atomic reads, guide G16).
__global__ __launch_bounds__(256) void histscan_kernel(
        const int* __restrict__ dst, int* __restrict__ cnt, int E,
        const float* __restrict__ Win, const float* __restrict__ Wg,
        const float* __restrict__ Wout,
        unsigned short* __restrict__ WinT, unsigned short* __restrict__ WgT,
        unsigned short* __restrict__ WoutT,
        unsigned* __restrict__ bsum, unsigned* __restrict__ boff, unsigned* __restrict__ done,
        int* __restrict__ rowptr,
        float* __restrict__ dis, float* __restrict__ selfn, int n, int nb) {
    const int b = blockIdx.x, tid = threadIdx.x;
    const int stride = nb * 256;

    // phase 0: weight transposes (grid-stride over 90112 elements)
    for (int i = b * 256 + tid; i < 90112; i += stride) {
        if (i < 16384) {                       // Win 128x128
            int m = i & 127, k = i >> 7;
            WinT[m * 128 + k] = f2bf(Win[i]);
        } else if (i < 81920) {                // Wg 4x128x128
            int j = i - 16384;
            int m = j & 127, k = (j >> 7) & 127, mat = j >> 14;
            WgT[mat * 16384 + m * 128 + k] = f2bf(Wg[j]);
        } else {                               // Wout 128x64
            int j = i - 81920;
            int m = j % 64, k = j / 64;
            WoutT[m * 128 + k] = f2bf(Wout[j]);
        }
    }
    // phase 1: degree histogram (grid-stride over E)
    for (int i = b * 256 + tid; i < E; i += stride)
        atomicAdd(&cnt[dst[i]], 1);

    // device-wide barrier: all blocks' histogram atomics complete
    __syncthreads();
    if (tid == 0) {
        __threadfence();
        atomicAdd(&done[0], 1u);
        while (atomicOr(&done[0], 0u) < (unsigned)nb)
            __builtin_amdgcn_s_sleep(8);
    }
    __syncthreads();

    // phase 2: exclusive scan (cnt read via atomic for cross-XCD coherence)
    __shared__ int s[256];
    __shared__ int s2[256];
    __shared__ int flag_agg;
    __shared__ int blkoff;
    int i = b * 256 + tid;
    int cc = (i < n) ? (int)atomicOr((unsigned*)&cnt[i], 0u) : 0;
    s[tid] = cc;
    __syncthreads();
    for (int off = 1; off < 256; off <<= 1) {   // inclusive scan in LDS
        int t = s[tid];
        int a = (tid >= off) ? s[tid - off] : 0;
        __syncthreads();
        s[tid] = t + a;
        __syncthreads();
    }
    if (tid == 0) {
        atomicExch(&bsum[b], (unsigned)s[255] | 0x80000000u);   // publish block total
        __threadfence();                                        // release
        unsigned t = atomicAdd(&done[1], 1u);
        flag_agg = (t == (unsigned)(nb - 1)) ? 1 : 0;           // last arrival aggregates
    }
    __syncthreads();
    if (flag_agg) {
        __threadfence();                                        // acquire
        unsigned val = (tid < nb) ? (atomicOr(&bsum[tid], 0u) & 0x7fffffffu) : 0u;
        s2[tid] = (int)val;
        __syncthreads();
        for (int off = 1; off < 256; off <<= 1) {
            int t = s2[tid];
            int a = (tid >= off) ? s2[tid - off] : 0;
            __syncthreads();
            s2[tid] = t + a;
            __syncthreads();
        }
        if (tid < nb)
            atomicExch(&boff[tid], ((unsigned)s2[tid] - val) | 0x80000000u); // exclusive
    }
    if (tid == 0) {
        unsigned vv;
        while (((vv = atomicOr(&boff[b], 0u)) & 0x80000000u) == 0u)
            __builtin_amdgcn_s_sleep(8);
        blkoff = (int)(vv & 0x7fffffffu);
    }
    __syncthreads();
    if (i < n) {
        int pre = blkoff + s[tid] - cc;       // exclusive prefix
        rowptr[i] = pre;
        float d = (float)cc + 1.0f;           // deg = in-degree + self-loop
        dis[i] = rsqrtf(d);
        selfn[i] = 1.0f / d;
        if (i == n - 1) rowptr[n] = pre + cc;
    }
}

// ---------- merged: mgemm2 (blocks [0,GB)) + CSR fill (blocks [GB, GB+FB)) ----------
// Independent work co-scheduled: MFMA-bound startup GEMMs overlap the
// write-allocate-bound edge scatter. Fill uses nontemporal 8B stores.
__global__ __launch_bounds__(256) void fillgemm_kernel(
        const float* __restrict__ X,
        const unsigned short* __restrict__ W1T, const float* __restrict__ b1,
        const unsigned short* __restrict__ W2T,
        unsigned short* __restrict__ H0, unsigned short* __restrict__ T0, int nrows, int GB,
        const int* __restrict__ src, const int* __restrict__ dst,
        int* __restrict__ cursor, const float* __restrict__ dis,
        unsigned long long* __restrict__ epack, int E) {
    __shared__ unsigned short Al[64 * 136];
    __shared__ unsigned short Wl[128 * 136];
    const int tid = threadIdx.x;

    if (blockIdx.x >= GB) {
        // ---------------- fill branch ----------------
        int i = (blockIdx.x - GB) * 256 + tid;
        if (i < E) {
            int s = src[i], d = dst[i];
            int p = atomicAdd(&cursor[d], 1);
            float w = dis[s] * dis[d];        // edge weight, constant across all 4 layers
            unsigned long long rec = (unsigned long long)(unsigned)s |
                                     ((unsigned long long)__float_as_uint(w) << 32);
            __builtin_nontemporal_store(rec, &epack[p]);
        }
        return;
    }

    // ---------------- mgemm2 branch ----------------
    const int w     = tid >> 6;
    const int lane  = tid & 63;
    const int col_l = lane & 15;
    const int quad  = lane >> 4;
    const int row_base = blockIdx.x * 64;

#pragma unroll
    for (int it = 0; it < 8; ++it) {
        int idx = it * 256 + tid;
        int r = idx >> 5, c4 = idx & 31;
        int gr = row_base + r; if (gr >= nrows) gr = nrows - 1;
        float4 v = *(const float4*)&X[(size_t)gr * 128 + c4 * 4];
        ushort4 u;
        u.x = f2bf(v.x); u.y = f2bf(v.y); u.z = f2bf(v.z); u.w = f2bf(v.w);
        *(ushort4*)&Al[r * 136 + c4 * 4] = u;
    }
#pragma unroll
    for (int it = 0; it < 8; ++it) {
        int idx = it * 256 + tid;
        int r = idx >> 4, ch = idx & 15;
        *(float4*)&Wl[r * 136 + ch * 8] = *(const float4*)&W1T[(size_t)r * 128 + ch * 8];
    }
    __syncthreads();

    short8 af[4];
    const int arow = w * 16 + col_l;
#pragma unroll
    for (int ks = 0; ks < 4; ++ks)
        af[ks] = *(const short8*)&Al[arow * 136 + ks * 32 + quad * 8];

    floatx4 acc[8];
#pragma unroll
    for (int ct = 0; ct < 8; ++ct) {
        acc[ct] = (floatx4){0.f, 0.f, 0.f, 0.f};
#pragma unroll
        for (int ks = 0; ks < 4; ++ks) {
            short8 bf = *(const short8*)&Wl[(ct * 16 + col_l) * 136 + ks * 32 + quad * 8];
            acc[ct] = __builtin_amdgcn_mfma_f32_16x16x32_bf16(af[ks], bf, acc[ct], 0, 0, 0);
        }
    }
    __syncthreads();   // all LDS reads done before overwrite

#pragma unroll
    for (int ct = 0; ct < 8; ++ct) {
        int col = ct * 16 + col_l;
        float bv = b1[col];
#pragma unroll
        for (int r = 0; r < 4; ++r) {
            int row_l = w * 16 + quad * 4 + r;
            float o = acc[ct][r] + bv;
            unsigned short ob = f2bf(o);
            Al[row_l * 136 + col] = ob;
            int gr = row_base + row_l;
            if (gr < nrows) H0[(size_t)gr * 128 + col] = ob;
        }
    }
#pragma unroll
    for (int it = 0; it < 8; ++it) {
        int idx = it * 256 + tid;
        int r = idx >> 4, ch = idx & 15;
        *(float4*)&Wl[r * 136 + ch * 8] = *(const float4*)&W2T[(size_t)r * 128 + ch * 8];
    }
    __syncthreads();

#pragma unroll
    for (int ks = 0; ks < 4; ++ks)
        af[ks] = *(const short8*)&Al[arow * 136 + ks * 32 + quad * 8];
#pragma unroll
    for (int ct = 0; ct < 8; ++ct) {
        acc[ct] = (floatx4){0.f, 0.f, 0.f, 0.f};
#pragma unroll
        for (int ks = 0; ks < 4; ++ks) {
            short8 bf = *(const short8*)&Wl[(ct * 16 + col_l) * 136 + ks * 32 + quad * 8];
            acc[ct] = __builtin_amdgcn_mfma_f32_16x16x32_bf16(af[ks], bf, acc[ct], 0, 0, 0);
        }
    }
#pragma unroll
    for (int ct = 0; ct < 8; ++ct) {
        int col = ct * 16 + col_l;
#pragma unroll
        for (int r = 0; r < 4; ++r) {
            int gr = row_base + w * 16 + quad * 4 + r;
            if (gr < nrows) T0[(size_t)gr * 128 + col] = f2bf(acc[ct][r]);
        }
    }
}

// ---------- fused BN(+skip+relu+ACC[bf16]) -> MFMA GEMM (AGG bf16) ----------
// stats come as 8 shards of 256 floats (sum[128], sumsq[128]); summed here.
template<int MO, bool STAGE_ACC, bool OB16>
__global__ __launch_bounds__(256) void mgemm_bn_kernel(
        const unsigned short* __restrict__ AGGB, const float* __restrict__ stats,
        const float* __restrict__ gamma, const float* __restrict__ beta,
        const unsigned short* __restrict__ XSKIP, unsigned short* __restrict__ ACC,
        const unsigned short* __restrict__ WT, const float* __restrict__ bias,
        void* __restrict__ C, int nrows, float inv_n, int do_skip, int first) {
    constexpr int NT = MO / 16;
    __shared__ unsigned short Al[64 * 136];
    __shared__ unsigned short Wl[MO * 136];
    __shared__ float ABl[256];
    const int tid   = threadIdx.x;
    const int w     = tid >> 6;
    const int lane  = tid & 63;
    const int col_l = lane & 15;
    const int quad  = lane >> 4;
    const int row_base = blockIdx.x * 64;

    if (tid < 128) {
        float s = 0.f, ss = 0.f;
#pragma unroll
        for (int k = 0; k < 8; ++k) {
            s  += stats[k * 256 + tid];
            ss += stats[k * 256 + 128 + tid];
        }
        float m = s * inv_n;
        float var = ss * inv_n - m * m;
        float inv = rsqrtf(var + 1e-5f);
        float Ax = inv * gamma[tid];
        ABl[tid] = Ax;
        ABl[128 + tid] = beta[tid] - m * Ax;
    }
#pragma unroll
    for (int it = 0; it < MO / 16; ++it) {
        int idx = it * 256 + tid;
        int r = idx >> 4, ch = idx & 15;
        *(float4*)&Wl[r * 136 + ch * 8] = *(const float4*)&WT[(size_t)r * 128 + ch * 8];
    }
    __syncthreads();

#pragma unroll
    for (int it = 0; it < 8; ++it) {
        int idx = it * 256 + tid;
        int r = idx >> 5, c4 = idx & 31;
        int gr = row_base + r;
        ushort4 hu = make_ushort4(0, 0, 0, 0);
        if (gr < nrows) {
            ushort4 xb = *(const ushort4*)&AGGB[(size_t)gr * 128 + c4 * 4];
            float4 Av = ((const float4*)ABl)[c4];
            float4 Bv = ((const float4*)ABl)[32 + c4];
            float4 t;
            t.x = fmaf(bf2f(xb.x), Av.x, Bv.x);
            t.y = fmaf(bf2f(xb.y), Av.y, Bv.y);
            t.z = fmaf(bf2f(xb.z), Av.z, Bv.z);
            t.w = fmaf(bf2f(xb.w), Av.w, Bv.w);
            if (do_skip) {
                ushort4 sk = *(const ushort4*)&XSKIP[(size_t)gr * 128 + c4 * 4];
                t.x = fmaf(0.5f, bf2f(sk.x), t.x);
                t.y = fmaf(0.5f, bf2f(sk.y), t.y);
                t.z = fmaf(0.5f, bf2f(sk.z), t.z);
                t.w = fmaf(0.5f, bf2f(sk.w), t.w);
            }
            t.x = fmaxf(t.x, 0.f); t.y = fmaxf(t.y, 0.f);
            t.z = fmaxf(t.z, 0.f); t.w = fmaxf(t.w, 0.f);
            float4 a;
            if (first) {
                a = t;
            } else {
                ushort4 ab = *(const ushort4*)&ACC[(size_t)gr * 128 + c4 * 4];
                a.x = bf2f(ab.x) + t.x;
                a.y = bf2f(ab.y) + t.y;
                a.z = bf2f(ab.z) + t.z;
                a.w = bf2f(ab.w) + t.w;
            }
            float4 sv;
            if (STAGE_ACC) sv = a; else sv = t;
            hu.x = f2bf(sv.x); hu.y = f2bf(sv.y); hu.z = f2bf(sv.z); hu.w = f2bf(sv.w);
            if (!STAGE_ACC) {
                ushort4 au;
                au.x = f2bf(a.x); au.y = f2bf(a.y); au.z = f2bf(a.z); au.w = f2bf(a.w);
                *(ushort4*)&ACC[(size_t)gr * 128 + c4 * 4] = au;
            }
        }
        *(ushort4*)&Al[r * 136 + c4 * 4] = hu;
    }
    __syncthreads();

    short8 af[4];
    const int arow = w * 16 + col_l;
#pragma unroll
    for (int ks = 0; ks < 4; ++ks)
        af[ks] = *(const short8*)&Al[arow * 136 + ks * 32 + quad * 8];

    floatx4 acc[NT];
#pragma unroll
    for (int ct = 0; ct < NT; ++ct) {
        acc[ct] = (floatx4){0.f, 0.f, 0.f, 0.f};
#pragma unroll
        for (int ks = 0; ks < 4; ++ks) {
            short8 bf = *(const short8*)&Wl[(ct * 16 + col_l) * 136 + ks * 32 + quad * 8];
            acc[ct] = __builtin_amdgcn_mfma_f32_16x16x32_bf16(af[ks], bf, acc[ct], 0, 0, 0);
        }
    }

#pragma unroll
    for (int ct = 0; ct < NT; ++ct) {
        int col = ct * 16 + col_l;
        float bv = bias ? bias[col] : 0.f;
#pragma unroll
        for (int r = 0; r < 4; ++r) {
            int gr = row_base + w * 16 + quad * 4 + r;
            if (gr < nrows) {
                float o = acc[ct][r] + bv;
                if (OB16) ((unsigned short*)C)[(size_t)gr * MO + col] = f2bf(o);
                else      ((float*)C)[(size_t)gr * MO + col] = o;
            }
        }
    }
}

// ---------- persistent CSR gather aggregation + fused BN stats ----------
// Plain (cached) epack loads: block->XCD mapping is stable across the 4 launches,
// so each block's epack slice stays L2-resident for layers 1-3.
__global__ __launch_bounds__(256) void aggstat_kernel(const unsigned short* __restrict__ T,
        const int* __restrict__ rowptr, const unsigned long long* __restrict__ epack,
        const float* __restrict__ selfn,
        unsigned short* __restrict__ AGGB, float* __restrict__ stats, int n, int nw) {
    const int w    = threadIdx.x >> 6;
    const int lane = threadIdx.x & 63;
    const int wid  = blockIdx.x * 4 + w;
    const int c    = lane * 2;
    float s1x = 0.f, s1y = 0.f, s2x = 0.f, s2y = 0.f;

    for (int v = wid; v < n; v += nw) {
        ushort2 tv = *(const ushort2*)&T[(size_t)v * 128 + c];
        float sn = selfn[v];
        float ax = bf2f(tv.x) * sn, ay = bf2f(tv.y) * sn;
        int e = rowptr[v], e1 = rowptr[v + 1];
        for (; e + 8 <= e1; e += 8) {
            unsigned long long d[8]; ushort2 t[8];
#pragma unroll
            for (int j = 0; j < 8; ++j) d[j] = epack[e + j];
#pragma unroll
            for (int j = 0; j < 8; ++j)
                t[j] = *(const ushort2*)&T[(size_t)(unsigned)d[j] * 128 + c];
#pragma unroll
            for (int j = 0; j < 8; ++j) {
                float wj = __uint_as_float((unsigned)(d[j] >> 32));
                ax = fmaf(wj, bf2f(t[j].x), ax);
                ay = fmaf(wj, bf2f(t[j].y), ay);
            }
        }
        for (; e + 4 <= e1; e += 4) {
            unsigned long long d[4]; ushort2 t[4];
#pragma unroll
            for (int j = 0; j < 4; ++j) d[j] = epack[e + j];
#pragma unroll
            for (int j = 0; j < 4; ++j)
                t[j] = *(const ushort2*)&T[(size_t)(unsigned)d[j] * 128 + c];
#pragma unroll
            for (int j = 0; j < 4; ++j) {
                float wj = __uint_as_float((unsigned)(d[j] >> 32));
                ax = fmaf(wj, bf2f(t[j].x), ax);
                ay = fmaf(wj, bf2f(t[j].y), ay);
            }
        }
        for (; e < e1; ++e) {
            unsigned long long d0 = epack[e];
            ushort2 tu = *(const ushort2*)&T[(size_t)(unsigned)d0 * 128 + c];
            float w0 = __uint_as_float((unsigned)(d0 >> 32));
            ax = fmaf(w0, bf2f(tu.x), ax);
            ay = fmaf(w0, bf2f(tu.y), ay);
        }
        ushort2 o; o.x = f2bf(ax); o.y = f2bf(ay);
        *(ushort2*)&AGGB[(size_t)v * 128 + c] = o;
        float rx = bf2f(o.x), ry = bf2f(o.y);   // stats on bf16-rounded values
        s1x += rx; s1y += ry;
        s2x = fmaf(rx, rx, s2x); s2y = fmaf(ry, ry, s2y);
    }

    __shared__ float r1[4][130];
    __shared__ float r2[4][130];
    r1[w][c] = s1x; r1[w][c + 1] = s1y;
    r2[w][c] = s2x; r2[w][c + 1] = s2y;
    __syncthreads();
    if (w == 0) {
        float a1 = r1[0][c] + r1[1][c] + r1[2][c] + r1[3][c];
        float b1 = r1[0][c + 1] + r1[1][c + 1] + r1[2][c + 1] + r1[3][c + 1];
        float a2 = r2[0][c] + r2[1][c] + r2[2][c] + r2[3][c];
        float b2 = r2[0][c + 1] + r2[1][c + 1] + r2[2][c + 1] + r2[3][c + 1];
        float* sh = stats + (blockIdx.x & 7) * 256;
        atomicAdd(&sh[c], a1);
        atomicAdd(&sh[c + 1], b1);
        atomicAdd(&sh[128 + c], a2);
        atomicAdd(&sh[128 + c + 1], b2);
    }
}

extern "C" void kernel_launch(void* const* d_in, const int* in_sizes, int n_in,
                              void* d_out, int out_size, void* d_ws, size_t ws_size,
                              hipStream_t stream) {
    (void)n_in; (void)out_size; (void)ws_size;
    const float* x    = (const float*)d_in[0];
    const float* Win  = (const float*)d_in[1];
    const float* bin  = (const float*)d_in[2];
    const float* Wg   = (const float*)d_in[3];
    // d_in[4] = b_g: cancelled by BN mean-subtract, unused.
    const float* gamma = (const float*)d_in[5];
    const float* beta  = (const float*)d_in[6];
    const float* Wout  = (const float*)d_in[7];
    const float* bout  = (const float*)d_in[8];
    const int*   eidx  = (const int*)d_in[9];
    float* out = (float*)d_out;

    const int N = in_sizes[0] / 128;   // 50000 nodes
    const int E = in_sizes[9] / 2;     // 600000 edges
    const int* esrc_in = eidx;
    const int* edst_in = eidx + E;

    char* p = (char*)d_ws;
    auto alloc = [&](size_t bytes) { char* r = p; p += (bytes + 255) & ~(size_t)255; return r; };
    const size_t NB2 = (size_t)N * 128 * sizeof(unsigned short);
    unsigned short* h0b   = (unsigned short*)alloc(NB2);  // x_skip (bf16)
    unsigned short* tb16  = (unsigned short*)alloc(NB2);  // t (bf16)
    unsigned short* aggb  = (unsigned short*)alloc(NB2);  // agg (bf16)
    unsigned short* accb  = (unsigned short*)alloc(NB2);  // ACC (bf16)
    unsigned short* WinT  = (unsigned short*)alloc(128 * 128 * 2);
    unsigned short* WgT   = (unsigned short*)alloc(4 * 128 * 128 * 2);
    unsigned short* WoutT = (unsigned short*)alloc(128 * 64 * 2);
    float* disb  = (float*)alloc((size_t)N * 4);
    float* selfn = (float*)alloc((size_t)N * 4);
    // ---- contiguous zero region: cnt | bsum | boff | done | stats4 ----
    char* z0 = p;
    int*      cnt    = (int*)alloc((size_t)N * 4);
    unsigned* bsum   = (unsigned*)alloc(256 * 4);
    unsigned* boff   = (unsigned*)alloc(256 * 4);
    unsigned* done   = (unsigned*)alloc(256);
    float*    stats4 = (float*)alloc((size_t)4 * 8 * 256 * 4);   // [layer][shard 0..7][256]
    const size_t zbytes = (size_t)(p - z0);
    int*   rowptr = (int*)alloc((size_t)(N + 1) * 4);
    int*   cursor = (int*)alloc((size_t)N * 4);
    unsigned long long* epack = (unsigned long long*)alloc((size_t)E * 8);

    auto cdiv = [](int a, int b) { return (a + b - 1) / b; };
    const int NBLK = cdiv(N, 256);     // 196 (must be <= 256 for histscan)
    const float inv_n = 1.0f / (float)N;
    const int AGG_BLOCKS = 2048;       // 8192 waves = full residency; ~6 nodes/wave
    const int AGG_WAVES  = AGG_BLOCKS * 4;
    const int GB = cdiv(N, 64);        // mgemm2 tile blocks (782)
    const int FB = cdiv(E, 256);       // fill blocks (2344)

    // graph preprocessing (weights + histogram + scan in ONE launch)
    hipMemsetAsync(z0, 0, zbytes, stream);
    histscan_kernel<<<NBLK, 256, 0, stream>>>(edst_in, cnt, E,
                                              Win, Wg, Wout, WinT, WgT, WoutT,
                                              bsum, boff, done, rowptr,
                                              disb, selfn, N, NBLK);
    // cursor starts at rowptr (copy during fill via separate small kernel is avoided:
    // seed cursor by reusing rowptr -> cursor copy inside fillgemm fill branch would race;
    // instead memcpy rowptr->cursor async)
    hipMemcpyAsync(cursor, rowptr, (size_t)N * 4, hipMemcpyDeviceToDevice, stream);

    // merged: startup GEMMs (h0 = x@W_in+b_in ; t0 = h0@Wg[0]) || CSR fill
    fillgemm_kernel<<<GB + FB, 256, 0, stream>>>(x, WinT, bin, WgT, h0b, tb16, N, GB,
                                                 esrc_in, edst_in, cursor, disb, epack, E);

    for (int i = 0; i < 4; ++i) {
        float* stats = stats4 + (size_t)i * 8 * 256;
        aggstat_kernel<<<AGG_BLOCKS, 256, 0, stream>>>(tb16, rowptr, epack, selfn,
                                                       aggb, stats, N, AGG_WAVES);
        if (i < 3) {
            mgemm_bn_kernel<128, false, true><<<cdiv(N, 64), 256, 0, stream>>>(
                aggb, stats, gamma + i * 128, beta + i * 128, h0b, accb,
                WgT + (size_t)(i + 1) * 128 * 128, nullptr, (void*)tb16, N,
                inv_n, (i & 1), (i == 0) ? 1 : 0);
        } else {
            mgemm_bn_kernel<64, true, false><<<cdiv(N, 64), 256, 0, stream>>>(
                aggb, stats, gamma + i * 128, beta + i * 128, h0b, accb,
                WoutT, bout, (void*)out, N, inv_n, 1, 0);
        }
    }
}

// Round 9
// 405.505 us; speedup vs baseline: 1.2424x; 1.0310x over previous
//
#include <hip/hip_runtime.h>

using short8  = __attribute__((ext_vector_type(8))) short;
using floatx4 = __attribute__((ext_vector_type(4))) float;

// ---------- bf16 helpers ----------
static __device__ __forceinline__ float bf2f(unsigned short u) {
    union { unsigned u; float f; } v; v.u = ((unsigned)u) << 16; return v.f;
}
static __device__ __forceinline__ unsigned short f2bf(float f) {
    union { float f; unsigned u; } v; v.f = f;
    unsigned r = v.u + 0x7FFFu + ((v.u >> 16) & 1u);   // round-to-nearest-even
    return (unsigned short)(r >> 16);
}

// ---------- fused: degree histogram + all weight transposes (full grid) ----------
__global__ void histw_kernel(const int* __restrict__ dst, int* __restrict__ cnt, int E,
                             const float* __restrict__ Win, const float* __restrict__ Wg,
                             const float* __restrict__ Wout,
                             unsigned short* __restrict__ WinT, unsigned short* __restrict__ WgT,
                             unsigned short* __restrict__ WoutT) {
    int HB = (E + 255) >> 8;
    int b = blockIdx.x;
    if (b < HB) {
        int i = b * 256 + threadIdx.x;
        if (i < E) atomicAdd(&cnt[dst[i]], 1);
    } else {
        int i = (b - HB) * 256 + threadIdx.x;
        if (i < 16384) {                       // Win 128x128
            int m = i & 127, k = i >> 7;
            WinT[m * 128 + k] = f2bf(Win[i]);
        } else if (i < 81920) {                // Wg 4x128x128
            int j = i - 16384;
            int m = j & 127, k = (j >> 7) & 127, mat = j >> 14;
            WgT[mat * 16384 + m * 128 + k] = f2bf(Wg[j]);
        } else if (i < 90112) {                // Wout 128x64
            int j = i - 81920;
            int m = j % 64, k = j / 64;
            WoutT[m * 128 + k] = f2bf(Wout[j]);
        }
    }
}

// ---------- single-kernel exclusive scan over cnt[0..n), nb <= 256 blocks ----------
__global__ __launch_bounds__(256) void scanall_kernel(const int* __restrict__ cnt,
        unsigned* __restrict__ bsum, unsigned* __restrict__ boff, unsigned* __restrict__ done,
        int* __restrict__ rowptr, int* __restrict__ cursor,
        float* __restrict__ dis, float* __restrict__ selfn, int n, int nb) {
    __shared__ int s[256];
    __shared__ int s2[256];
    __shared__ int flag_agg;
    __shared__ int blkoff;
    const int b = blockIdx.x, tid = threadIdx.x;
    int i = b * 256 + tid;
    int cc = (i < n) ? cnt[i] : 0;
    s[tid] = cc;
    __syncthreads();
    for (int off = 1; off < 256; off <<= 1) {   // inclusive scan in LDS
        int t = s[tid];
        int a = (tid >= off) ? s[tid - off] : 0;
        __syncthreads();
        s[tid] = t + a;
        __syncthreads();
    }
    if (tid == 0) {
        atomicExch(&bsum[b], (unsigned)s[255] | 0x80000000u);   // publish block total
        __threadfence();                                        // release
        unsigned t = atomicAdd(done, 1u);
        flag_agg = (t == (unsigned)(nb - 1)) ? 1 : 0;           // last arrival aggregates
    }
    __syncthreads();
    if (flag_agg) {
        __threadfence();                                        // acquire
        unsigned val = (tid < nb) ? (atomicOr(&bsum[tid], 0u) & 0x7fffffffu) : 0u;
        s2[tid] = (int)val;
        __syncthreads();
        for (int off = 1; off < 256; off <<= 1) {
            int t = s2[tid];
            int a = (tid >= off) ? s2[tid - off] : 0;
            __syncthreads();
            s2[tid] = t + a;
            __syncthreads();
        }
        if (tid < nb)
            atomicExch(&boff[tid], ((unsigned)s2[tid] - val) | 0x80000000u); // exclusive
    }
    if (tid == 0) {
        unsigned vv;
        while (((vv = atomicOr(&boff[b], 0u)) & 0x80000000u) == 0u)
            __builtin_amdgcn_s_sleep(8);
        blkoff = (int)(vv & 0x7fffffffu);
    }
    __syncthreads();
    if (i < n) {
        int pre = blkoff + s[tid] - cc;       // exclusive prefix
        rowptr[i] = pre;
        cursor[i] = pre;
        float d = (float)cc + 1.0f;           // deg = in-degree + self-loop
        dis[i] = rsqrtf(d);
        selfn[i] = 1.0f / d;
        if (i == n - 1) rowptr[n] = pre + cc;
    }
}

// ---------- merged: mgemm2 (blocks [0,GB)) + CSR fill (blocks [GB, GB+FB)) ----------
// Independent work co-scheduled: MFMA-bound startup GEMMs overlap the
// write-allocate-bound edge scatter.
__global__ __launch_bounds__(256) void fillgemm_kernel(
        const float* __restrict__ X,
        const unsigned short* __restrict__ W1T, const float* __restrict__ b1,
        const unsigned short* __restrict__ W2T,
        unsigned short* __restrict__ H0, unsigned short* __restrict__ T0, int nrows, int GB,
        const int* __restrict__ src, const int* __restrict__ dst,
        int* __restrict__ cursor, const float* __restrict__ dis,
        unsigned long long* __restrict__ epack, int E) {
    __shared__ unsigned short Al[64 * 136];
    __shared__ unsigned short Wl[128 * 136];
    const int tid = threadIdx.x;

    if (blockIdx.x >= GB) {
        // ---------------- fill branch ----------------
        int i = (blockIdx.x - GB) * 256 + tid;
        if (i < E) {
            int s = src[i], d = dst[i];
            int p = atomicAdd(&cursor[d], 1);
            float w = dis[s] * dis[d];        // edge weight, constant across all 4 layers
            unsigned long long rec = (unsigned long long)(unsigned)s |
                                     ((unsigned long long)__float_as_uint(w) << 32);
            __builtin_nontemporal_store(rec, &epack[p]);
        }
        return;
    }

    // ---------------- mgemm2 branch ----------------
    const int w     = tid >> 6;
    const int lane  = tid & 63;
    const int col_l = lane & 15;
    const int quad  = lane >> 4;
    const int row_base = blockIdx.x * 64;

#pragma unroll
    for (int it = 0; it < 8; ++it) {
        int idx = it * 256 + tid;
        int r = idx >> 5, c4 = idx & 31;
        int gr = row_base + r; if (gr >= nrows) gr = nrows - 1;
        float4 v = *(const float4*)&X[(size_t)gr * 128 + c4 * 4];
        ushort4 u;
        u.x = f2bf(v.x); u.y = f2bf(v.y); u.z = f2bf(v.z); u.w = f2bf(v.w);
        *(ushort4*)&Al[r * 136 + c4 * 4] = u;
    }
#pragma unroll
    for (int it = 0; it < 8; ++it) {
        int idx = it * 256 + tid;
        int r = idx >> 4, ch = idx & 15;
        *(float4*)&Wl[r * 136 + ch * 8] = *(const float4*)&W1T[(size_t)r * 128 + ch * 8];
    }
    __syncthreads();

    short8 af[4];
    const int arow = w * 16 + col_l;
#pragma unroll
    for (int ks = 0; ks < 4; ++ks)
        af[ks] = *(const short8*)&Al[arow * 136 + ks * 32 + quad * 8];

    floatx4 acc[8];
#pragma unroll
    for (int ct = 0; ct < 8; ++ct) {
        acc[ct] = (floatx4){0.f, 0.f, 0.f, 0.f};
#pragma unroll
        for (int ks = 0; ks < 4; ++ks) {
            short8 bf = *(const short8*)&Wl[(ct * 16 + col_l) * 136 + ks * 32 + quad * 8];
            acc[ct] = __builtin_amdgcn_mfma_f32_16x16x32_bf16(af[ks], bf, acc[ct], 0, 0, 0);
        }
    }
    __syncthreads();   // all LDS reads done before overwrite

#pragma unroll
    for (int ct = 0; ct < 8; ++ct) {
        int col = ct * 16 + col_l;
        float bv = b1[col];
#pragma unroll
        for (int r = 0; r < 4; ++r) {
            int row_l = w * 16 + quad * 4 + r;
            float o = acc[ct][r] + bv;
            unsigned short ob = f2bf(o);
            Al[row_l * 136 + col] = ob;
            int gr = row_base + row_l;
            if (gr < nrows) H0[(size_t)gr * 128 + col] = ob;
        }
    }
#pragma unroll
    for (int it = 0; it < 8; ++it) {
        int idx = it * 256 + tid;
        int r = idx >> 4, ch = idx & 15;
        *(float4*)&Wl[r * 136 + ch * 8] = *(const float4*)&W2T[(size_t)r * 128 + ch * 8];
    }
    __syncthreads();

#pragma unroll
    for (int ks = 0; ks < 4; ++ks)
        af[ks] = *(const short8*)&Al[arow * 136 + ks * 32 + quad * 8];
#pragma unroll
    for (int ct = 0; ct < 8; ++ct) {
        acc[ct] = (floatx4){0.f, 0.f, 0.f, 0.f};
#pragma unroll
        for (int ks = 0; ks < 4; ++ks) {
            short8 bf = *(const short8*)&Wl[(ct * 16 + col_l) * 136 + ks * 32 + quad * 8];
            acc[ct] = __builtin_amdgcn_mfma_f32_16x16x32_bf16(af[ks], bf, acc[ct], 0, 0, 0);
        }
    }
#pragma unroll
    for (int ct = 0; ct < 8; ++ct) {
        int col = ct * 16 + col_l;
#pragma unroll
        for (int r = 0; r < 4; ++r) {
            int gr = row_base + w * 16 + quad * 4 + r;
            if (gr < nrows) T0[(size_t)gr * 128 + col] = f2bf(acc[ct][r]);
        }
    }
}

// ---------- fused BN(+skip+relu+ACC[bf16]) -> MFMA GEMM (AGG bf16) ----------
// stats come as 8 shards of 256 floats (sum[128], sumsq[128]); summed here.
template<int MO, bool STAGE_ACC, bool OB16>
__global__ __launch_bounds__(256) void mgemm_bn_kernel(
        const unsigned short* __restrict__ AGGB, const float* __restrict__ stats,
        const float* __restrict__ gamma, const float* __restrict__ beta,
        const unsigned short* __restrict__ XSKIP, unsigned short* __restrict__ ACC,
        const unsigned short* __restrict__ WT, const float* __restrict__ bias,
        void* __restrict__ C, int nrows, float inv_n, int do_skip, int first) {
    constexpr int NT = MO / 16;
    __shared__ unsigned short Al[64 * 136];
    __shared__ unsigned short Wl[MO * 136];
    __shared__ float ABl[256];
    const int tid   = threadIdx.x;
    const int w     = tid >> 6;
    const int lane  = tid & 63;
    const int col_l = lane & 15;
    const int quad  = lane >> 4;
    const int row_base = blockIdx.x * 64;

    if (tid < 128) {
        float s = 0.f, ss = 0.f;
#pragma unroll
        for (int k = 0; k < 8; ++k) {
            s  += stats[k * 256 + tid];
            ss += stats[k * 256 + 128 + tid];
        }
        float m = s * inv_n;
        float var = ss * inv_n - m * m;
        float inv = rsqrtf(var + 1e-5f);
        float Ax = inv * gamma[tid];
        ABl[tid] = Ax;
        ABl[128 + tid] = beta[tid] - m * Ax;
    }
#pragma unroll
    for (int it = 0; it < MO / 16; ++it) {
        int idx = it * 256 + tid;
        int r = idx >> 4, ch = idx & 15;
        *(float4*)&Wl[r * 136 + ch * 8] = *(const float4*)&WT[(size_t)r * 128 + ch * 8];
    }
    __syncthreads();

#pragma unroll
    for (int it = 0; it < 8; ++it) {
        int idx = it * 256 + tid;
        int r = idx >> 5, c4 = idx & 31;
        int gr = row_base + r;
        ushort4 hu = make_ushort4(0, 0, 0, 0);
        if (gr < nrows) {
            ushort4 xb = *(const ushort4*)&AGGB[(size_t)gr * 128 + c4 * 4];
            float4 Av = ((const float4*)ABl)[c4];
            float4 Bv = ((const float4*)ABl)[32 + c4];
            float4 t;
            t.x = fmaf(bf2f(xb.x), Av.x, Bv.x);
            t.y = fmaf(bf2f(xb.y), Av.y, Bv.y);
            t.z = fmaf(bf2f(xb.z), Av.z, Bv.z);
            t.w = fmaf(bf2f(xb.w), Av.w, Bv.w);
            if (do_skip) {
                ushort4 sk = *(const ushort4*)&XSKIP[(size_t)gr * 128 + c4 * 4];
                t.x = fmaf(0.5f, bf2f(sk.x), t.x);
                t.y = fmaf(0.5f, bf2f(sk.y), t.y);
                t.z = fmaf(0.5f, bf2f(sk.z), t.z);
                t.w = fmaf(0.5f, bf2f(sk.w), t.w);
            }
            t.x = fmaxf(t.x, 0.f); t.y = fmaxf(t.y, 0.f);
            t.z = fmaxf(t.z, 0.f); t.w = fmaxf(t.w, 0.f);
            float4 a;
            if (first) {
                a = t;
            } else {
                ushort4 ab = *(const ushort4*)&ACC[(size_t)gr * 128 + c4 * 4];
                a.x = bf2f(ab.x) + t.x;
                a.y = bf2f(ab.y) + t.y;
                a.z = bf2f(ab.z) + t.z;
                a.w = bf2f(ab.w) + t.w;
            }
            float4 sv;
            if (STAGE_ACC) sv = a; else sv = t;
            hu.x = f2bf(sv.x); hu.y = f2bf(sv.y); hu.z = f2bf(sv.z); hu.w = f2bf(sv.w);
            if (!STAGE_ACC) {
                ushort4 au;
                au.x = f2bf(a.x); au.y = f2bf(a.y); au.z = f2bf(a.z); au.w = f2bf(a.w);
                *(ushort4*)&ACC[(size_t)gr * 128 + c4 * 4] = au;
            }
        }
        *(ushort4*)&Al[r * 136 + c4 * 4] = hu;
    }
    __syncthreads();

    short8 af[4];
    const int arow = w * 16 + col_l;
#pragma unroll
    for (int ks = 0; ks < 4; ++ks)
        af[ks] = *(const short8*)&Al[arow * 136 + ks * 32 + quad * 8];

    floatx4 acc[NT];
#pragma unroll
    for (int ct = 0; ct < NT; ++ct) {
        acc[ct] = (floatx4){0.f, 0.f, 0.f, 0.f};
#pragma unroll
        for (int ks = 0; ks < 4; ++ks) {
            short8 bf = *(const short8*)&Wl[(ct * 16 + col_l) * 136 + ks * 32 + quad * 8];
            acc[ct] = __builtin_amdgcn_mfma_f32_16x16x32_bf16(af[ks], bf, acc[ct], 0, 0, 0);
        }
    }

#pragma unroll
    for (int ct = 0; ct < NT; ++ct) {
        int col = ct * 16 + col_l;
        float bv = bias ? bias[col] : 0.f;
#pragma unroll
        for (int r = 0; r < 4; ++r) {
            int gr = row_base + w * 16 + quad * 4 + r;
            if (gr < nrows) {
                float o = acc[ct][r] + bv;
                if (OB16) ((unsigned short*)C)[(size_t)gr * MO + col] = f2bf(o);
                else      ((float*)C)[(size_t)gr * MO + col] = o;
            }
        }
    }
}

// ---------- persistent CSR gather aggregation + fused BN stats ----------
// Plain (cached) epack loads: block->XCD mapping is stable across the 4 launches,
// so each block's epack slice stays L2-resident for layers 1-3.
__global__ __launch_bounds__(256) void aggstat_kernel(const unsigned short* __restrict__ T,
        const int* __restrict__ rowptr, const unsigned long long* __restrict__ epack,
        const float* __restrict__ selfn,
        unsigned short* __restrict__ AGGB, float* __restrict__ stats, int n, int nw) {
    const int w    = threadIdx.x >> 6;
    const int lane = threadIdx.x & 63;
    const int wid  = blockIdx.x * 4 + w;
    const int c    = lane * 2;
    float s1x = 0.f, s1y = 0.f, s2x = 0.f, s2y = 0.f;

    for (int v = wid; v < n; v += nw) {
        ushort2 tv = *(const ushort2*)&T[(size_t)v * 128 + c];
        float sn = selfn[v];
        float ax = bf2f(tv.x) * sn, ay = bf2f(tv.y) * sn;
        int e = rowptr[v], e1 = rowptr[v + 1];
        for (; e + 8 <= e1; e += 8) {
            unsigned long long d[8]; ushort2 t[8];
#pragma unroll
            for (int j = 0; j < 8; ++j) d[j] = epack[e + j];
#pragma unroll
            for (int j = 0; j < 8; ++j)
                t[j] = *(const ushort2*)&T[(size_t)(unsigned)d[j] * 128 + c];
#pragma unroll
            for (int j = 0; j < 8; ++j) {
                float wj = __uint_as_float((unsigned)(d[j] >> 32));
                ax = fmaf(wj, bf2f(t[j].x), ax);
                ay = fmaf(wj, bf2f(t[j].y), ay);
            }
        }
        for (; e + 4 <= e1; e += 4) {
            unsigned long long d[4]; ushort2 t[4];
#pragma unroll
            for (int j = 0; j < 4; ++j) d[j] = epack[e + j];
#pragma unroll
            for (int j = 0; j < 4; ++j)
                t[j] = *(const ushort2*)&T[(size_t)(unsigned)d[j] * 128 + c];
#pragma unroll
            for (int j = 0; j < 4; ++j) {
                float wj = __uint_as_float((unsigned)(d[j] >> 32));
                ax = fmaf(wj, bf2f(t[j].x), ax);
                ay = fmaf(wj, bf2f(t[j].y), ay);
            }
        }
        for (; e < e1; ++e) {
            unsigned long long d0 = epack[e];
            ushort2 tu = *(const ushort2*)&T[(size_t)(unsigned)d0 * 128 + c];
            float w0 = __uint_as_float((unsigned)(d0 >> 32));
            ax = fmaf(w0, bf2f(tu.x), ax);
            ay = fmaf(w0, bf2f(tu.y), ay);
        }
        ushort2 o; o.x = f2bf(ax); o.y = f2bf(ay);
        *(ushort2*)&AGGB[(size_t)v * 128 + c] = o;
        float rx = bf2f(o.x), ry = bf2f(o.y);   // stats on bf16-rounded values
        s1x += rx; s1y += ry;
        s2x = fmaf(rx, rx, s2x); s2y = fmaf(ry, ry, s2y);
    }

    __shared__ float r1[4][130];
    __shared__ float r2[4][130];
    r1[w][c] = s1x; r1[w][c + 1] = s1y;
    r2[w][c] = s2x; r2[w][c + 1] = s2y;
    __syncthreads();
    if (w == 0) {
        float a1 = r1[0][c] + r1[1][c] + r1[2][c] + r1[3][c];
        float b1 = r1[0][c + 1] + r1[1][c + 1] + r1[2][c + 1] + r1[3][c + 1];
        float a2 = r2[0][c] + r2[1][c] + r2[2][c] + r2[3][c];
        float b2 = r2[0][c + 1] + r2[1][c + 1] + r2[2][c + 1] + r2[3][c + 1];
        float* sh = stats + (blockIdx.x & 7) * 256;
        atomicAdd(&sh[c], a1);
        atomicAdd(&sh[c + 1], b1);
        atomicAdd(&sh[128 + c], a2);
        atomicAdd(&sh[128 + c + 1], b2);
    }
}

extern "C" void kernel_launch(void* const* d_in, const int* in_sizes, int n_in,
                              void* d_out, int out_size, void* d_ws, size_t ws_size,
                              hipStream_t stream) {
    (void)n_in; (void)out_size; (void)ws_size;
    const float* x    = (const float*)d_in[0];
    const float* Win  = (const float*)d_in[1];
    const float* bin  = (const float*)d_in[2];
    const float* Wg   = (const float*)d_in[3];
    // d_in[4] = b_g: cancelled by BN mean-subtract, unused.
    const float* gamma = (const float*)d_in[5];
    const float* beta  = (const float*)d_in[6];
    const float* Wout  = (const float*)d_in[7];
    const float* bout  = (const float*)d_in[8];
    const int*   eidx  = (const int*)d_in[9];
    float* out = (float*)d_out;

    const int N = in_sizes[0] / 128;   // 50000 nodes
    const int E = in_sizes[9] / 2;     // 600000 edges
    const int* esrc_in = eidx;
    const int* edst_in = eidx + E;

    char* p = (char*)d_ws;
    auto alloc = [&](size_t bytes) { char* r = p; p += (bytes + 255) & ~(size_t)255; return r; };
    const size_t NB2 = (size_t)N * 128 * sizeof(unsigned short);
    unsigned short* h0b   = (unsigned short*)alloc(NB2);  // x_skip (bf16)
    unsigned short* tb16  = (unsigned short*)alloc(NB2);  // t (bf16)
    unsigned short* aggb  = (unsigned short*)alloc(NB2);  // agg (bf16)
    unsigned short* accb  = (unsigned short*)alloc(NB2);  // ACC (bf16)
    unsigned short* WinT  = (unsigned short*)alloc(128 * 128 * 2);
    unsigned short* WgT   = (unsigned short*)alloc(4 * 128 * 128 * 2);
    unsigned short* WoutT = (unsigned short*)alloc(128 * 64 * 2);
    float* disb  = (float*)alloc((size_t)N * 4);
    float* selfn = (float*)alloc((size_t)N * 4);
    // ---- contiguous zero region: cnt | bsum | boff | done | stats4 ----
    char* z0 = p;
    int*      cnt    = (int*)alloc((size_t)N * 4);
    unsigned* bsum   = (unsigned*)alloc(256 * 4);
    unsigned* boff   = (unsigned*)alloc(256 * 4);
    unsigned* done   = (unsigned*)alloc(256);
    float*    stats4 = (float*)alloc((size_t)4 * 8 * 256 * 4);   // [layer][shard 0..7][256]
    const size_t zbytes = (size_t)(p - z0);
    int*   rowptr = (int*)alloc((size_t)(N + 1) * 4);
    int*   cursor = (int*)alloc((size_t)N * 4);
    unsigned long long* epack = (unsigned long long*)alloc((size_t)E * 8);

    auto cdiv = [](int a, int b) { return (a + b - 1) / b; };
    const int NBLK = cdiv(N, 256);     // 196 (must be <= 256 for scanall)
    const float inv_n = 1.0f / (float)N;
    const int AGG_BLOCKS = 2048;       // 8192 waves = full residency; ~6 nodes/wave
    const int AGG_WAVES  = AGG_BLOCKS * 4;
    const int GB = cdiv(N, 64);        // mgemm2 tile blocks (782)
    const int FB = cdiv(E, 256);       // fill blocks (2344)

    // graph preprocessing (+ weight transposes fused into the hist launch)
    hipMemsetAsync(z0, 0, zbytes, stream);
    histw_kernel<<<cdiv(E, 256) + 352, 256, 0, stream>>>(edst_in, cnt, E,
                                                         Win, Wg, Wout, WinT, WgT, WoutT);
    scanall_kernel<<<NBLK, 256, 0, stream>>>(cnt, bsum, boff, done, rowptr, cursor,
                                             disb, selfn, N, NBLK);

    // merged: startup GEMMs (h0 = x@W_in+b_in ; t0 = h0@Wg[0]) || CSR fill
    fillgemm_kernel<<<GB + FB, 256, 0, stream>>>(x, WinT, bin, WgT, h0b, tb16, N, GB,
                                                 esrc_in, edst_in, cursor, disb, epack, E);

    for (int i = 0; i < 4; ++i) {
        float* stats = stats4 + (size_t)i * 8 * 256;
        aggstat_kernel<<<AGG_BLOCKS, 256, 0, stream>>>(tb16, rowptr, epack, selfn,
                                                       aggb, stats, N, AGG_WAVES);
        if (i < 3) {
            mgemm_bn_kernel<128, false, true><<<cdiv(N, 64), 256, 0, stream>>>(
                aggb, stats, gamma + i * 128, beta + i * 128, h0b, accb,
                WgT + (size_t)(i + 1) * 128 * 128, nullptr, (void*)tb16, N,
                inv_n, (i & 1), (i == 0) ? 1 : 0);
        } else {
            mgemm_bn_kernel<64, true, false><<<cdiv(N, 64), 256, 0, stream>>>(
                aggb, stats, gamma + i * 128, beta + i * 128, h0b, accb,
                WoutT, bout, (void*)out, N, inv_n, 1, 0);
        }
    }
}

// Round 10
// 404.290 us; speedup vs baseline: 1.2462x; 1.0030x over previous
//
#include <hip/hip_runtime.h>

using short8  = __attribute__((ext_vector_type(8))) short;
using floatx4 = __attribute__((ext_vector_type(4))) float;

// ---------- bf16 helpers ----------
static __device__ __forceinline__ float bf2f(unsigned short u) {
    union { unsigned u; float f; } v; v.u = ((unsigned)u) << 16; return v.f;
}
static __device__ __forceinline__ unsigned short f2bf(float f) {
    union { float f; unsigned u; } v; v.f = f;
    unsigned r = v.u + 0x7FFFu + ((v.u >> 16) & 1u);   // round-to-nearest-even
    return (unsigned short)(r >> 16);
}

// ---------- fused: degree histogram + all weight transposes (full grid) ----------
__global__ void histw_kernel(const int* __restrict__ dst, int* __restrict__ cnt, int E,
                             const float* __restrict__ Win, const float* __restrict__ Wg,
                             const float* __restrict__ Wout,
                             unsigned short* __restrict__ WinT, unsigned short* __restrict__ WgT,
                             unsigned short* __restrict__ WoutT) {
    int HB = (E + 255) >> 8;
    int b = blockIdx.x;
    if (b < HB) {
        int i = b * 256 + threadIdx.x;
        if (i < E) atomicAdd(&cnt[dst[i]], 1);
    } else {
        int i = (b - HB) * 256 + threadIdx.x;
        if (i < 16384) {                       // Win 128x128
            int m = i & 127, k = i >> 7;
            WinT[m * 128 + k] = f2bf(Win[i]);
        } else if (i < 81920) {                // Wg 4x128x128
            int j = i - 16384;
            int m = j & 127, k = (j >> 7) & 127, mat = j >> 14;
            WgT[mat * 16384 + m * 128 + k] = f2bf(Wg[j]);
        } else if (i < 90112) {                // Wout 128x64
            int j = i - 81920;
            int m = j % 64, k = j / 64;
            WoutT[m * 128 + k] = f2bf(Wout[j]);
        }
    }
}

// ---------- single-kernel exclusive scan over cnt[0..n), nb <= 256 blocks ----------
__global__ __launch_bounds__(256) void scanall_kernel(const int* __restrict__ cnt,
        unsigned* __restrict__ bsum, unsigned* __restrict__ boff, unsigned* __restrict__ done,
        int* __restrict__ rowptr, int* __restrict__ cursor,
        float* __restrict__ dis, float* __restrict__ selfn, int n, int nb) {
    __shared__ int s[256];
    __shared__ int s2[256];
    __shared__ int flag_agg;
    __shared__ int blkoff;
    const int b = blockIdx.x, tid = threadIdx.x;
    int i = b * 256 + tid;
    int cc = (i < n) ? cnt[i] : 0;
    s[tid] = cc;
    __syncthreads();
    for (int off = 1; off < 256; off <<= 1) {   // inclusive scan in LDS
        int t = s[tid];
        int a = (tid >= off) ? s[tid - off] : 0;
        __syncthreads();
        s[tid] = t + a;
        __syncthreads();
    }
    if (tid == 0) {
        atomicExch(&bsum[b], (unsigned)s[255] | 0x80000000u);   // publish block total
        __threadfence();                                        // release
        unsigned t = atomicAdd(done, 1u);
        flag_agg = (t == (unsigned)(nb - 1)) ? 1 : 0;           // last arrival aggregates
    }
    __syncthreads();
    if (flag_agg) {
        __threadfence();                                        // acquire
        unsigned val = (tid < nb) ? (atomicOr(&bsum[tid], 0u) & 0x7fffffffu) : 0u;
        s2[tid] = (int)val;
        __syncthreads();
        for (int off = 1; off < 256; off <<= 1) {
            int t = s2[tid];
            int a = (tid >= off) ? s2[tid - off] : 0;
            __syncthreads();
            s2[tid] = t + a;
            __syncthreads();
        }
        if (tid < nb)
            atomicExch(&boff[tid], ((unsigned)s2[tid] - val) | 0x80000000u); // exclusive
    }
    if (tid == 0) {
        unsigned vv;
        while (((vv = atomicOr(&boff[b], 0u)) & 0x80000000u) == 0u)
            __builtin_amdgcn_s_sleep(8);
        blkoff = (int)(vv & 0x7fffffffu);
    }
    __syncthreads();
    if (i < n) {
        int pre = blkoff + s[tid] - cc;       // exclusive prefix
        rowptr[i] = pre;
        cursor[i] = pre;
        float d = (float)cc + 1.0f;           // deg = in-degree + self-loop
        dis[i] = rsqrtf(d);
        selfn[i] = 1.0f / d;
        if (i == n - 1) rowptr[n] = pre + cc;
    }
}

// ---------- merged: mgemm2 (blocks [0,GB)) + XCD-affine CSR fill (blocks >= GB) ----------
// Fill: dst space is chunked into 512-node ranges, range (d>>9)&7 committed only by
// blocks with blockIdx&7 == that range (round-robin block->XCD). All writers of any
// epack line / cursor address then live on ONE XCD -> no L2 line bouncing. Each
// 256-edge window is scanned by 8 consecutive blocks (one per range): 8x sequential
// reads (L2/LLC absorbed) traded for the scattered write-allocate storm.
__global__ __launch_bounds__(256) void fillgemm_kernel(
        const float* __restrict__ X,
        const unsigned short* __restrict__ W1T, const float* __restrict__ b1,
        const unsigned short* __restrict__ W2T,
        unsigned short* __restrict__ H0, unsigned short* __restrict__ T0, int nrows, int GB,
        const int* __restrict__ src, const int* __restrict__ dst,
        int* __restrict__ cursor, const float* __restrict__ dis,
        unsigned long long* __restrict__ epack, int E) {
    __shared__ unsigned short Al[64 * 136];
    __shared__ unsigned short Wl[128 * 136];
    const int tid = threadIdx.x;

    if (blockIdx.x >= GB) {
        // ---------------- fill branch ----------------
        int myr = blockIdx.x & 7;                       // XCD id (round-robin heuristic)
        int i = ((blockIdx.x - GB) >> 3) * 256 + tid;   // edge window shared by 8 blocks
        if (i < E) {
            int d = dst[i];
            if (((d >> 9) & 7) == myr) {                // this XCD's dst range
                int s = src[i];
                int p = atomicAdd(&cursor[d], 1);
                float w = dis[s] * dis[d];   // edge weight, constant across all 4 layers
                epack[p] = (unsigned long long)(unsigned)s |
                           ((unsigned long long)__float_as_uint(w) << 32);
            }
        }
        return;
    }

    // ---------------- mgemm2 branch ----------------
    const int w     = tid >> 6;
    const int lane  = tid & 63;
    const int col_l = lane & 15;
    const int quad  = lane >> 4;
    const int row_base = blockIdx.x * 64;

#pragma unroll
    for (int it = 0; it < 8; ++it) {
        int idx = it * 256 + tid;
        int r = idx >> 5, c4 = idx & 31;
        int gr = row_base + r; if (gr >= nrows) gr = nrows - 1;
        float4 v = *(const float4*)&X[(size_t)gr * 128 + c4 * 4];
        ushort4 u;
        u.x = f2bf(v.x); u.y = f2bf(v.y); u.z = f2bf(v.z); u.w = f2bf(v.w);
        *(ushort4*)&Al[r * 136 + c4 * 4] = u;
    }
#pragma unroll
    for (int it = 0; it < 8; ++it) {
        int idx = it * 256 + tid;
        int r = idx >> 4, ch = idx & 15;
        *(float4*)&Wl[r * 136 + ch * 8] = *(const float4*)&W1T[(size_t)r * 128 + ch * 8];
    }
    __syncthreads();

    short8 af[4];
    const int arow = w * 16 + col_l;
#pragma unroll
    for (int ks = 0; ks < 4; ++ks)
        af[ks] = *(const short8*)&Al[arow * 136 + ks * 32 + quad * 8];

    floatx4 acc[8];
#pragma unroll
    for (int ct = 0; ct < 8; ++ct) {
        acc[ct] = (floatx4){0.f, 0.f, 0.f, 0.f};
#pragma unroll
        for (int ks = 0; ks < 4; ++ks) {
            short8 bf = *(const short8*)&Wl[(ct * 16 + col_l) * 136 + ks * 32 + quad * 8];
            acc[ct] = __builtin_amdgcn_mfma_f32_16x16x32_bf16(af[ks], bf, acc[ct], 0, 0, 0);
        }
    }
    __syncthreads();   // all LDS reads done before overwrite

#pragma unroll
    for (int ct = 0; ct < 8; ++ct) {
        int col = ct * 16 + col_l;
        float bv = b1[col];
#pragma unroll
        for (int r = 0; r < 4; ++r) {
            int row_l = w * 16 + quad * 4 + r;
            float o = acc[ct][r] + bv;
            unsigned short ob = f2bf(o);
            Al[row_l * 136 + col] = ob;
            int gr = row_base + row_l;
            if (gr < nrows) H0[(size_t)gr * 128 + col] = ob;
        }
    }
#pragma unroll
    for (int it = 0; it < 8; ++it) {
        int idx = it * 256 + tid;
        int r = idx >> 4, ch = idx & 15;
        *(float4*)&Wl[r * 136 + ch * 8] = *(const float4*)&W2T[(size_t)r * 128 + ch * 8];
    }
    __syncthreads();

#pragma unroll
    for (int ks = 0; ks < 4; ++ks)
        af[ks] = *(const short8*)&Al[arow * 136 + ks * 32 + quad * 8];
#pragma unroll
    for (int ct = 0; ct < 8; ++ct) {
        acc[ct] = (floatx4){0.f, 0.f, 0.f, 0.f};
#pragma unroll
        for (int ks = 0; ks < 4; ++ks) {
            short8 bf = *(const short8*)&Wl[(ct * 16 + col_l) * 136 + ks * 32 + quad * 8];
            acc[ct] = __builtin_amdgcn_mfma_f32_16x16x32_bf16(af[ks], bf, acc[ct], 0, 0, 0);
        }
    }
#pragma unroll
    for (int ct = 0; ct < 8; ++ct) {
        int col = ct * 16 + col_l;
#pragma unroll
        for (int r = 0; r < 4; ++r) {
            int gr = row_base + w * 16 + quad * 4 + r;
            if (gr < nrows) T0[(size_t)gr * 128 + col] = f2bf(acc[ct][r]);
        }
    }
}

// ---------- fused BN(+skip+relu+ACC[bf16]) -> MFMA GEMM (AGG bf16) ----------
// stats come as 8 shards of 256 floats (sum[128], sumsq[128]); summed here.
template<int MO, bool STAGE_ACC, bool OB16>
__global__ __launch_bounds__(256) void mgemm_bn_kernel(
        const unsigned short* __restrict__ AGGB, const float* __restrict__ stats,
        const float* __restrict__ gamma, const float* __restrict__ beta,
        const unsigned short* __restrict__ XSKIP, unsigned short* __restrict__ ACC,
        const unsigned short* __restrict__ WT, const float* __restrict__ bias,
        void* __restrict__ C, int nrows, float inv_n, int do_skip, int first) {
    constexpr int NT = MO / 16;
    __shared__ unsigned short Al[64 * 136];
    __shared__ unsigned short Wl[MO * 136];
    __shared__ float ABl[256];
    const int tid   = threadIdx.x;
    const int w     = tid >> 6;
    const int lane  = tid & 63;
    const int col_l = lane & 15;
    const int quad  = lane >> 4;
    const int row_base = blockIdx.x * 64;

    if (tid < 128) {
        float s = 0.f, ss = 0.f;
#pragma unroll
        for (int k = 0; k < 8; ++k) {
            s  += stats[k * 256 + tid];
            ss += stats[k * 256 + 128 + tid];
        }
        float m = s * inv_n;
        float var = ss * inv_n - m * m;
        float inv = rsqrtf(var + 1e-5f);
        float Ax = inv * gamma[tid];
        ABl[tid] = Ax;
        ABl[128 + tid] = beta[tid] - m * Ax;
    }
#pragma unroll
    for (int it = 0; it < MO / 16; ++it) {
        int idx = it * 256 + tid;
        int r = idx >> 4, ch = idx & 15;
        *(float4*)&Wl[r * 136 + ch * 8] = *(const float4*)&WT[(size_t)r * 128 + ch * 8];
    }
    __syncthreads();

#pragma unroll
    for (int it = 0; it < 8; ++it) {
        int idx = it * 256 + tid;
        int r = idx >> 5, c4 = idx & 31;
        int gr = row_base + r;
        ushort4 hu = make_ushort4(0, 0, 0, 0);
        if (gr < nrows) {
            ushort4 xb = *(const ushort4*)&AGGB[(size_t)gr * 128 + c4 * 4];
            float4 Av = ((const float4*)ABl)[c4];
            float4 Bv = ((const float4*)ABl)[32 + c4];
            float4 t;
            t.x = fmaf(bf2f(xb.x), Av.x, Bv.x);
            t.y = fmaf(bf2f(xb.y), Av.y, Bv.y);
            t.z = fmaf(bf2f(xb.z), Av.z, Bv.z);
            t.w = fmaf(bf2f(xb.w), Av.w, Bv.w);
            if (do_skip) {
                ushort4 sk = *(const ushort4*)&XSKIP[(size_t)gr * 128 + c4 * 4];
                t.x = fmaf(0.5f, bf2f(sk.x), t.x);
                t.y = fmaf(0.5f, bf2f(sk.y), t.y);
                t.z = fmaf(0.5f, bf2f(sk.z), t.z);
                t.w = fmaf(0.5f, bf2f(sk.w), t.w);
            }
            t.x = fmaxf(t.x, 0.f); t.y = fmaxf(t.y, 0.f);
            t.z = fmaxf(t.z, 0.f); t.w = fmaxf(t.w, 0.f);
            float4 a;
            if (first) {
                a = t;
            } else {
                ushort4 ab = *(const ushort4*)&ACC[(size_t)gr * 128 + c4 * 4];
                a.x = bf2f(ab.x) + t.x;
                a.y = bf2f(ab.y) + t.y;
                a.z = bf2f(ab.z) + t.z;
                a.w = bf2f(ab.w) + t.w;
            }
            float4 sv;
            if (STAGE_ACC) sv = a; else sv = t;
            hu.x = f2bf(sv.x); hu.y = f2bf(sv.y); hu.z = f2bf(sv.z); hu.w = f2bf(sv.w);
            if (!STAGE_ACC) {
                ushort4 au;
                au.x = f2bf(a.x); au.y = f2bf(a.y); au.z = f2bf(a.z); au.w = f2bf(a.w);
                *(ushort4*)&ACC[(size_t)gr * 128 + c4 * 4] = au;
            }
        }
        *(ushort4*)&Al[r * 136 + c4 * 4] = hu;
    }
    __syncthreads();

    short8 af[4];
    const int arow = w * 16 + col_l;
#pragma unroll
    for (int ks = 0; ks < 4; ++ks)
        af[ks] = *(const short8*)&Al[arow * 136 + ks * 32 + quad * 8];

    floatx4 acc[NT];
#pragma unroll
    for (int ct = 0; ct < NT; ++ct) {
        acc[ct] = (floatx4){0.f, 0.f, 0.f, 0.f};
#pragma unroll
        for (int ks = 0; ks < 4; ++ks) {
            short8 bf = *(const short8*)&Wl[(ct * 16 + col_l) * 136 + ks * 32 + quad * 8];
            acc[ct] = __builtin_amdgcn_mfma_f32_16x16x32_bf16(af[ks], bf, acc[ct], 0, 0, 0);
        }
    }

#pragma unroll
    for (int ct = 0; ct < NT; ++ct) {
        int col = ct * 16 + col_l;
        float bv = bias ? bias[col] : 0.f;
#pragma unroll
        for (int r = 0; r < 4; ++r) {
            int gr = row_base + w * 16 + quad * 4 + r;
            if (gr < nrows) {
                float o = acc[ct][r] + bv;
                if (OB16) ((unsigned short*)C)[(size_t)gr * MO + col] = f2bf(o);
                else      ((float*)C)[(size_t)gr * MO + col] = o;
            }
        }
    }
}

// ---------- persistent CSR gather aggregation + fused BN stats ----------
__global__ __launch_bounds__(256) void aggstat_kernel(const unsigned short* __restrict__ T,
        const int* __restrict__ rowptr, const unsigned long long* __restrict__ epack,
        const float* __restrict__ selfn,
        unsigned short* __restrict__ AGGB, float* __restrict__ stats, int n, int nw) {
    const int w    = threadIdx.x >> 6;
    const int lane = threadIdx.x & 63;
    const int wid  = blockIdx.x * 4 + w;
    const int c    = lane * 2;
    float s1x = 0.f, s1y = 0.f, s2x = 0.f, s2y = 0.f;

    for (int v = wid; v < n; v += nw) {
        ushort2 tv = *(const ushort2*)&T[(size_t)v * 128 + c];
        float sn = selfn[v];
        float ax = bf2f(tv.x) * sn, ay = bf2f(tv.y) * sn;
        int e = rowptr[v], e1 = rowptr[v + 1];
        for (; e + 8 <= e1; e += 8) {
            unsigned long long d[8]; ushort2 t[8];
#pragma unroll
            for (int j = 0; j < 8; ++j) d[j] = epack[e + j];
#pragma unroll
            for (int j = 0; j < 8; ++j)
                t[j] = *(const ushort2*)&T[(size_t)(unsigned)d[j] * 128 + c];
#pragma unroll
            for (int j = 0; j < 8; ++j) {
                float wj = __uint_as_float((unsigned)(d[j] >> 32));
                ax = fmaf(wj, bf2f(t[j].x), ax);
                ay = fmaf(wj, bf2f(t[j].y), ay);
            }
        }
        for (; e + 4 <= e1; e += 4) {
            unsigned long long d[4]; ushort2 t[4];
#pragma unroll
            for (int j = 0; j < 4; ++j) d[j] = epack[e + j];
#pragma unroll
            for (int j = 0; j < 4; ++j)
                t[j] = *(const ushort2*)&T[(size_t)(unsigned)d[j] * 128 + c];
#pragma unroll
            for (int j = 0; j < 4; ++j) {
                float wj = __uint_as_float((unsigned)(d[j] >> 32));
                ax = fmaf(wj, bf2f(t[j].x), ax);
                ay = fmaf(wj, bf2f(t[j].y), ay);
            }
        }
        for (; e < e1; ++e) {
            unsigned long long d0 = epack[e];
            ushort2 tu = *(const ushort2*)&T[(size_t)(unsigned)d0 * 128 + c];
            float w0 = __uint_as_float((unsigned)(d0 >> 32));
            ax = fmaf(w0, bf2f(tu.x), ax);
            ay = fmaf(w0, bf2f(tu.y), ay);
        }
        ushort2 o; o.x = f2bf(ax); o.y = f2bf(ay);
        *(ushort2*)&AGGB[(size_t)v * 128 + c] = o;
        float rx = bf2f(o.x), ry = bf2f(o.y);   // stats on bf16-rounded values
        s1x += rx; s1y += ry;
        s2x = fmaf(rx, rx, s2x); s2y = fmaf(ry, ry, s2y);
    }

    __shared__ float r1[4][130];
    __shared__ float r2[4][130];
    r1[w][c] = s1x; r1[w][c + 1] = s1y;
    r2[w][c] = s2x; r2[w][c + 1] = s2y;
    __syncthreads();
    if (w == 0) {
        float a1 = r1[0][c] + r1[1][c] + r1[2][c] + r1[3][c];
        float b1 = r1[0][c + 1] + r1[1][c + 1] + r1[2][c + 1] + r1[3][c + 1];
        float a2 = r2[0][c] + r2[1][c] + r2[2][c] + r2[3][c];
        float b2 = r2[0][c + 1] + r2[1][c + 1] + r2[2][c + 1] + r2[3][c + 1];
        float* sh = stats + (blockIdx.x & 7) * 256;
        atomicAdd(&sh[c], a1);
        atomicAdd(&sh[c + 1], b1);
        atomicAdd(&sh[128 + c], a2);
        atomicAdd(&sh[128 + c + 1], b2);
    }
}

extern "C" void kernel_launch(void* const* d_in, const int* in_sizes, int n_in,
                              void* d_out, int out_size, void* d_ws, size_t ws_size,
                              hipStream_t stream) {
    (void)n_in; (void)out_size; (void)ws_size;
    const float* x    = (const float*)d_in[0];
    const float* Win  = (const float*)d_in[1];
    const float* bin  = (const float*)d_in[2];
    const float* Wg   = (const float*)d_in[3];
    // d_in[4] = b_g: cancelled by BN mean-subtract, unused.
    const float* gamma = (const float*)d_in[5];
    const float* beta  = (const float*)d_in[6];
    const float* Wout  = (const float*)d_in[7];
    const float* bout  = (const float*)d_in[8];
    const int*   eidx  = (const int*)d_in[9];
    float* out = (float*)d_out;

    const int N = in_sizes[0] / 128;   // 50000 nodes
    const int E = in_sizes[9] / 2;     // 600000 edges
    const int* esrc_in = eidx;
    const int* edst_in = eidx + E;

    char* p = (char*)d_ws;
    auto alloc = [&](size_t bytes) { char* r = p; p += (bytes + 255) & ~(size_t)255; return r; };
    const size_t NB2 = (size_t)N * 128 * sizeof(unsigned short);
    unsigned short* h0b   = (unsigned short*)alloc(NB2);  // x_skip (bf16)
    unsigned short* tb16  = (unsigned short*)alloc(NB2);  // t (bf16)
    unsigned short* aggb  = (unsigned short*)alloc(NB2);  // agg (bf16)
    unsigned short* accb  = (unsigned short*)alloc(NB2);  // ACC (bf16)
    unsigned short* WinT  = (unsigned short*)alloc(128 * 128 * 2);
    unsigned short* WgT   = (unsigned short*)alloc(4 * 128 * 128 * 2);
    unsigned short* WoutT = (unsigned short*)alloc(128 * 64 * 2);
    float* disb  = (float*)alloc((size_t)N * 4);
    float* selfn = (float*)alloc((size_t)N * 4);
    // ---- contiguous zero region: cnt | bsum | boff | done | stats4 ----
    char* z0 = p;
    int*      cnt    = (int*)alloc((size_t)N * 4);
    unsigned* bsum   = (unsigned*)alloc(256 * 4);
    unsigned* boff   = (unsigned*)alloc(256 * 4);
    unsigned* done   = (unsigned*)alloc(256);
    float*    stats4 = (float*)alloc((size_t)4 * 8 * 256 * 4);   // [layer][shard 0..7][256]
    const size_t zbytes = (size_t)(p - z0);
    int*   rowptr = (int*)alloc((size_t)(N + 1) * 4);
    int*   cursor = (int*)alloc((size_t)N * 4);
    unsigned long long* epack = (unsigned long long*)alloc((size_t)E * 8);

    auto cdiv = [](int a, int b) { return (a + b - 1) / b; };
    const int NBLK = cdiv(N, 256);     // 196 (must be <= 256 for scanall)
    const float inv_n = 1.0f / (float)N;
    const int AGG_BLOCKS = 2048;       // 8192 waves = full residency; ~6 nodes/wave
    const int AGG_WAVES  = AGG_BLOCKS * 4;
    const int GB = cdiv(N, 64);        // mgemm2 tile blocks (782)
    const int FB = 8 * cdiv(E, 256);   // fill blocks: 8 ranges x edge windows (18752)

    // graph preprocessing (+ weight transposes fused into the hist launch)
    hipMemsetAsync(z0, 0, zbytes, stream);
    histw_kernel<<<cdiv(E, 256) + 352, 256, 0, stream>>>(edst_in, cnt, E,
                                                         Win, Wg, Wout, WinT, WgT, WoutT);
    scanall_kernel<<<NBLK, 256, 0, stream>>>(cnt, bsum, boff, done, rowptr, cursor,
                                             disb, selfn, N, NBLK);

    // merged: startup GEMMs (h0 = x@W_in+b_in ; t0 = h0@Wg[0]) || XCD-affine CSR fill
    fillgemm_kernel<<<GB + FB, 256, 0, stream>>>(x, WinT, bin, WgT, h0b, tb16, N, GB,
                                                 esrc_in, edst_in, cursor, disb, epack, E);

    for (int i = 0; i < 4; ++i) {
        float* stats = stats4 + (size_t)i * 8 * 256;
        aggstat_kernel<<<AGG_BLOCKS, 256, 0, stream>>>(tb16, rowptr, epack, selfn,
                                                       aggb, stats, N, AGG_WAVES);
        if (i < 3) {
            mgemm_bn_kernel<128, false, true><<<cdiv(N, 64), 256, 0, stream>>>(
                aggb, stats, gamma + i * 128, beta + i * 128, h0b, accb,
                WgT + (size_t)(i + 1) * 128 * 128, nullptr, (void*)tb16, N,
                inv_n, (i & 1), (i == 0) ? 1 : 0);
        } else {
            mgemm_bn_kernel<64, true, false><<<cdiv(N, 64), 256, 0, stream>>>(
                aggb, stats, gamma + i * 128, beta + i * 128, h0b, accb,
                WoutT, bout, (void*)out, N, inv_n, 1, 0);
        }
    }
}

// Round 11
// 372.277 us; speedup vs baseline: 1.3533x; 1.0860x over previous
//
#include <hip/hip_runtime.h>

using short8  = __attribute__((ext_vector_type(8))) short;
using floatx4 = __attribute__((ext_vector_type(4))) float;

// ---------- bf16 helpers ----------
static __device__ __forceinline__ float bf2f(unsigned short u) {
    union { unsigned u; float f; } v; v.u = ((unsigned)u) << 16; return v.f;
}
static __device__ __forceinline__ unsigned short f2bf(float f) {
    union { float f; unsigned u; } v; v.f = f;
    unsigned r = v.u + 0x7FFFu + ((v.u >> 16) & 1u);   // round-to-nearest-even
    return (unsigned short)(r >> 16);
}

// ---------- fused: degree histogram + all weight transposes (full grid) ----------
__global__ void histw_kernel(const int* __restrict__ dst, int* __restrict__ cnt, int E,
                             const float* __restrict__ Win, const float* __restrict__ Wg,
                             const float* __restrict__ Wout,
                             unsigned short* __restrict__ WinT, unsigned short* __restrict__ WgT,
                             unsigned short* __restrict__ WoutT) {
    int HB = (E + 255) >> 8;
    int b = blockIdx.x;
    if (b < HB) {
        int i = b * 256 + threadIdx.x;
        if (i < E) atomicAdd(&cnt[dst[i]], 1);
    } else {
        int i = (b - HB) * 256 + threadIdx.x;
        if (i < 16384) {                       // Win 128x128
            int m = i & 127, k = i >> 7;
            WinT[m * 128 + k] = f2bf(Win[i]);
        } else if (i < 81920) {                // Wg 4x128x128
            int j = i - 16384;
            int m = j & 127, k = (j >> 7) & 127, mat = j >> 14;
            WgT[mat * 16384 + m * 128 + k] = f2bf(Wg[j]);
        } else if (i < 90112) {                // Wout 128x64
            int j = i - 81920;
            int m = j % 64, k = j / 64;
            WoutT[m * 128 + k] = f2bf(Wout[j]);
        }
    }
}

// ---------- single-kernel exclusive scan over cnt[0..n), nb <= 256 blocks ----------
__global__ __launch_bounds__(256) void scanall_kernel(const int* __restrict__ cnt,
        unsigned* __restrict__ bsum, unsigned* __restrict__ boff, unsigned* __restrict__ done,
        int* __restrict__ rowptr, int* __restrict__ cursor,
        float* __restrict__ dis, float* __restrict__ selfn, int n, int nb) {
    __shared__ int s[256];
    __shared__ int s2[256];
    __shared__ int flag_agg;
    __shared__ int blkoff;
    const int b = blockIdx.x, tid = threadIdx.x;
    int i = b * 256 + tid;
    int cc = (i < n) ? cnt[i] : 0;
    s[tid] = cc;
    __syncthreads();
    for (int off = 1; off < 256; off <<= 1) {   // inclusive scan in LDS
        int t = s[tid];
        int a = (tid >= off) ? s[tid - off] : 0;
        __syncthreads();
        s[tid] = t + a;
        __syncthreads();
    }
    if (tid == 0) {
        atomicExch(&bsum[b], (unsigned)s[255] | 0x80000000u);   // publish block total
        __threadfence();                                        // release
        unsigned t = atomicAdd(done, 1u);
        flag_agg = (t == (unsigned)(nb - 1)) ? 1 : 0;           // last arrival aggregates
    }
    __syncthreads();
    if (flag_agg) {
        __threadfence();                                        // acquire
        unsigned val = (tid < nb) ? (atomicOr(&bsum[tid], 0u) & 0x7fffffffu) : 0u;
        s2[tid] = (int)val;
        __syncthreads();
        for (int off = 1; off < 256; off <<= 1) {
            int t = s2[tid];
            int a = (tid >= off) ? s2[tid - off] : 0;
            __syncthreads();
            s2[tid] = t + a;
            __syncthreads();
        }
        if (tid < nb)
            atomicExch(&boff[tid], ((unsigned)s2[tid] - val) | 0x80000000u); // exclusive
    }
    if (tid == 0) {
        unsigned vv;
        while (((vv = atomicOr(&boff[b], 0u)) & 0x80000000u) == 0u)
            __builtin_amdgcn_s_sleep(8);
        blkoff = (int)(vv & 0x7fffffffu);
    }
    __syncthreads();
    if (i < n) {
        int pre = blkoff + s[tid] - cc;       // exclusive prefix
        rowptr[i] = pre;
        cursor[i] = pre;
        float d = (float)cc + 1.0f;           // deg = in-degree + self-loop
        dis[i] = rsqrtf(d);
        selfn[i] = 1.0f / d;
        if (i == n - 1) rowptr[n] = pre + cc;
    }
}

// ---------- merged: mgemm2 (blocks [0,GB)) + XCD-affine CSR fill (blocks >= GB) ----------
__global__ __launch_bounds__(256) void fillgemm_kernel(
        const float* __restrict__ X,
        const unsigned short* __restrict__ W1T, const float* __restrict__ b1,
        const unsigned short* __restrict__ W2T,
        unsigned short* __restrict__ H0, unsigned short* __restrict__ T0, int nrows, int GB,
        const int* __restrict__ src, const int* __restrict__ dst,
        int* __restrict__ cursor, const float* __restrict__ dis,
        unsigned long long* __restrict__ epack, int E) {
    __shared__ unsigned short Al[64 * 136];
    __shared__ unsigned short Wl[128 * 136];
    const int tid = threadIdx.x;

    if (blockIdx.x >= GB) {
        // ---------------- fill branch (XCD-affine dst ranges) ----------------
        int myr = blockIdx.x & 7;                       // XCD id (round-robin heuristic)
        int i = ((blockIdx.x - GB) >> 3) * 256 + tid;   // edge window shared by 8 blocks
        if (i < E) {
            int d = dst[i];
            if (((d >> 9) & 7) == myr) {                // this XCD's dst range
                int s = src[i];
                int p = atomicAdd(&cursor[d], 1);
                float w = dis[s] * dis[d];   // edge weight, constant across all 4 layers
                epack[p] = (unsigned long long)(unsigned)s |
                           ((unsigned long long)__float_as_uint(w) << 32);
            }
        }
        return;
    }

    // ---------------- mgemm2 branch ----------------
    const int w     = tid >> 6;
    const int lane  = tid & 63;
    const int col_l = lane & 15;
    const int quad  = lane >> 4;
    const int row_base = blockIdx.x * 64;

#pragma unroll
    for (int it = 0; it < 8; ++it) {
        int idx = it * 256 + tid;
        int r = idx >> 5, c4 = idx & 31;
        int gr = row_base + r; if (gr >= nrows) gr = nrows - 1;
        float4 v = *(const float4*)&X[(size_t)gr * 128 + c4 * 4];
        ushort4 u;
        u.x = f2bf(v.x); u.y = f2bf(v.y); u.z = f2bf(v.z); u.w = f2bf(v.w);
        *(ushort4*)&Al[r * 136 + c4 * 4] = u;
    }
#pragma unroll
    for (int it = 0; it < 8; ++it) {
        int idx = it * 256 + tid;
        int r = idx >> 4, ch = idx & 15;
        *(float4*)&Wl[r * 136 + ch * 8] = *(const float4*)&W1T[(size_t)r * 128 + ch * 8];
    }
    __syncthreads();

    short8 af[4];
    const int arow = w * 16 + col_l;
#pragma unroll
    for (int ks = 0; ks < 4; ++ks)
        af[ks] = *(const short8*)&Al[arow * 136 + ks * 32 + quad * 8];

    floatx4 acc[8];
#pragma unroll
    for (int ct = 0; ct < 8; ++ct) {
        acc[ct] = (floatx4){0.f, 0.f, 0.f, 0.f};
#pragma unroll
        for (int ks = 0; ks < 4; ++ks) {
            short8 bf = *(const short8*)&Wl[(ct * 16 + col_l) * 136 + ks * 32 + quad * 8];
            acc[ct] = __builtin_amdgcn_mfma_f32_16x16x32_bf16(af[ks], bf, acc[ct], 0, 0, 0);
        }
    }
    __syncthreads();   // all LDS reads done before overwrite

#pragma unroll
    for (int ct = 0; ct < 8; ++ct) {
        int col = ct * 16 + col_l;
        float bv = b1[col];
#pragma unroll
        for (int r = 0; r < 4; ++r) {
            int row_l = w * 16 + quad * 4 + r;
            float o = acc[ct][r] + bv;
            unsigned short ob = f2bf(o);
            Al[row_l * 136 + col] = ob;
            int gr = row_base + row_l;
            if (gr < nrows) H0[(size_t)gr * 128 + col] = ob;
        }
    }
#pragma unroll
    for (int it = 0; it < 8; ++it) {
        int idx = it * 256 + tid;
        int r = idx >> 4, ch = idx & 15;
        *(float4*)&Wl[r * 136 + ch * 8] = *(const float4*)&W2T[(size_t)r * 128 + ch * 8];
    }
    __syncthreads();

#pragma unroll
    for (int ks = 0; ks < 4; ++ks)
        af[ks] = *(const short8*)&Al[arow * 136 + ks * 32 + quad * 8];
#pragma unroll
    for (int ct = 0; ct < 8; ++ct) {
        acc[ct] = (floatx4){0.f, 0.f, 0.f, 0.f};
#pragma unroll
        for (int ks = 0; ks < 4; ++ks) {
            short8 bf = *(const short8*)&Wl[(ct * 16 + col_l) * 136 + ks * 32 + quad * 8];
            acc[ct] = __builtin_amdgcn_mfma_f32_16x16x32_bf16(af[ks], bf, acc[ct], 0, 0, 0);
        }
    }
#pragma unroll
    for (int ct = 0; ct < 8; ++ct) {
        int col = ct * 16 + col_l;
#pragma unroll
        for (int r = 0; r < 4; ++r) {
            int gr = row_base + w * 16 + quad * 4 + r;
            if (gr < nrows) T0[(size_t)gr * 128 + col] = f2bf(acc[ct][r]);
        }
    }
}

// ---------- fused BN(+skip+relu+ACC[bf16]) -> MFMA GEMM, A-fragments direct from global ----------
// Lane owns exactly A-fragment elements (row w*16+(lane&15), cols ks*32+quad*8..+8):
// loads AGG ushort8 from global (L2-resident), transforms in registers, RMWs ACC,
// packs bf16 af[] directly. No A-tile LDS, one fewer barrier, LDS ~36KB -> 4 blocks/CU.
template<int MO, bool STAGE_ACC, bool OB16>
__global__ __launch_bounds__(256) void mgemm_bn_kernel(
        const unsigned short* __restrict__ AGGB, const float* __restrict__ stats,
        const float* __restrict__ gamma, const float* __restrict__ beta,
        const unsigned short* __restrict__ XSKIP, unsigned short* __restrict__ ACC,
        const unsigned short* __restrict__ WT, const float* __restrict__ bias,
        void* __restrict__ C, int nrows, float inv_n, int do_skip, int first) {
    constexpr int NT = MO / 16;
    __shared__ unsigned short Wl[MO * 136];
    __shared__ float ABl[256];
    const int tid   = threadIdx.x;
    const int w     = tid >> 6;
    const int lane  = tid & 63;
    const int col_l = lane & 15;
    const int quad  = lane >> 4;
    const int row_base = blockIdx.x * 64;

    if (tid < 128) {
        float s = 0.f, ss = 0.f;
#pragma unroll
        for (int k = 0; k < 8; ++k) {
            s  += stats[k * 256 + tid];
            ss += stats[k * 256 + 128 + tid];
        }
        float m = s * inv_n;
        float var = ss * inv_n - m * m;
        float inv = rsqrtf(var + 1e-5f);
        float Ax = inv * gamma[tid];
        ABl[tid] = Ax;
        ABl[128 + tid] = beta[tid] - m * Ax;
    }
#pragma unroll
    for (int it = 0; it < MO / 16; ++it) {
        int idx = it * 256 + tid;
        int r = idx >> 4, ch = idx & 15;
        *(float4*)&Wl[r * 136 + ch * 8] = *(const float4*)&WT[(size_t)r * 128 + ch * 8];
    }
    __syncthreads();

    const int arow = w * 16 + col_l;
    const int gr   = row_base + arow;
    short8 af[4];
#pragma unroll
    for (int ks = 0; ks < 4; ++ks) {
        short8 a8 = {0, 0, 0, 0, 0, 0, 0, 0};
        if (gr < nrows) {
            const int cb = ks * 32 + quad * 8;
            short8 xb = *(const short8*)&AGGB[(size_t)gr * 128 + cb];
            short8 sk;
            if (do_skip) sk = *(const short8*)&XSKIP[(size_t)gr * 128 + cb];
            short8 ab;
            if (!first) ab = *(const short8*)&ACC[(size_t)gr * 128 + cb];
            short8 au;
#pragma unroll
            for (int j = 0; j < 8; ++j) {
                float t = fmaf(bf2f((unsigned short)xb[j]), ABl[cb + j], ABl[128 + cb + j]);
                if (do_skip) t = fmaf(0.5f, bf2f((unsigned short)sk[j]), t);
                t = fmaxf(t, 0.f);
                float a = first ? t : (bf2f((unsigned short)ab[j]) + t);
                float sv = STAGE_ACC ? a : t;
                a8[j] = (short)f2bf(sv);
                if (!STAGE_ACC) au[j] = (short)f2bf(a);
            }
            if (!STAGE_ACC) *(short8*)&ACC[(size_t)gr * 128 + cb] = au;
        }
        af[ks] = a8;
    }

    floatx4 acc[NT];
#pragma unroll
    for (int ct = 0; ct < NT; ++ct) {
        acc[ct] = (floatx4){0.f, 0.f, 0.f, 0.f};
#pragma unroll
        for (int ks = 0; ks < 4; ++ks) {
            short8 bf = *(const short8*)&Wl[(ct * 16 + col_l) * 136 + ks * 32 + quad * 8];
            acc[ct] = __builtin_amdgcn_mfma_f32_16x16x32_bf16(af[ks], bf, acc[ct], 0, 0, 0);
        }
    }

#pragma unroll
    for (int ct = 0; ct < NT; ++ct) {
        int col = ct * 16 + col_l;
        float bv = bias ? bias[col] : 0.f;
#pragma unroll
        for (int r = 0; r < 4; ++r) {
            int grr = row_base + w * 16 + quad * 4 + r;
            if (grr < nrows) {
                float o = acc[ct][r] + bv;
                if (OB16) ((unsigned short*)C)[(size_t)grr * MO + col] = f2bf(o);
                else      ((float*)C)[(size_t)grr * MO + col] = o;
            }
        }
    }
}

// ---------- persistent CSR gather aggregation + fused BN stats ----------
__global__ __launch_bounds__(256) void aggstat_kernel(const unsigned short* __restrict__ T,
        const int* __restrict__ rowptr, const unsigned long long* __restrict__ epack,
        const float* __restrict__ selfn,
        unsigned short* __restrict__ AGGB, float* __restrict__ stats, int n, int nw) {
    const int w    = threadIdx.x >> 6;
    const int lane = threadIdx.x & 63;
    const int wid  = blockIdx.x * 4 + w;
    const int c    = lane * 2;
    float s1x = 0.f, s1y = 0.f, s2x = 0.f, s2y = 0.f;

    for (int v = wid; v < n; v += nw) {
        ushort2 tv = *(const ushort2*)&T[(size_t)v * 128 + c];
        float sn = selfn[v];
        float ax = bf2f(tv.x) * sn, ay = bf2f(tv.y) * sn;
        int e = rowptr[v], e1 = rowptr[v + 1];
        for (; e + 8 <= e1; e += 8) {
            unsigned long long d[8]; ushort2 t[8];
#pragma unroll
            for (int j = 0; j < 8; ++j) d[j] = epack[e + j];
#pragma unroll
            for (int j = 0; j < 8; ++j)
                t[j] = *(const ushort2*)&T[(size_t)(unsigned)d[j] * 128 + c];
#pragma unroll
            for (int j = 0; j < 8; ++j) {
                float wj = __uint_as_float((unsigned)(d[j] >> 32));
                ax = fmaf(wj, bf2f(t[j].x), ax);
                ay = fmaf(wj, bf2f(t[j].y), ay);
            }
        }
        for (; e + 4 <= e1; e += 4) {
            unsigned long long d[4]; ushort2 t[4];
#pragma unroll
            for (int j = 0; j < 4; ++j) d[j] = epack[e + j];
#pragma unroll
            for (int j = 0; j < 4; ++j)
                t[j] = *(const ushort2*)&T[(size_t)(unsigned)d[j] * 128 + c];
#pragma unroll
            for (int j = 0; j < 4; ++j) {
                float wj = __uint_as_float((unsigned)(d[j] >> 32));
                ax = fmaf(wj, bf2f(t[j].x), ax);
                ay = fmaf(wj, bf2f(t[j].y), ay);
            }
        }
        for (; e < e1; ++e) {
            unsigned long long d0 = epack[e];
            ushort2 tu = *(const ushort2*)&T[(size_t)(unsigned)d0 * 128 + c];
            float w0 = __uint_as_float((unsigned)(d0 >> 32));
            ax = fmaf(w0, bf2f(tu.x), ax);
            ay = fmaf(w0, bf2f(tu.y), ay);
        }
        ushort2 o; o.x = f2bf(ax); o.y = f2bf(ay);
        *(ushort2*)&AGGB[(size_t)v * 128 + c] = o;
        float rx = bf2f(o.x), ry = bf2f(o.y);   // stats on bf16-rounded values
        s1x += rx; s1y += ry;
        s2x = fmaf(rx, rx, s2x); s2y = fmaf(ry, ry, s2y);
    }

    __shared__ float r1[4][130];
    __shared__ float r2[4][130];
    r1[w][c] = s1x; r1[w][c + 1] = s1y;
    r2[w][c] = s2x; r2[w][c + 1] = s2y;
    __syncthreads();
    if (w == 0) {
        float a1 = r1[0][c] + r1[1][c] + r1[2][c] + r1[3][c];
        float b1 = r1[0][c + 1] + r1[1][c + 1] + r1[2][c + 1] + r1[3][c + 1];
        float a2 = r2[0][c] + r2[1][c] + r2[2][c] + r2[3][c];
        float b2 = r2[0][c + 1] + r2[1][c + 1] + r2[2][c + 1] + r2[3][c + 1];
        float* sh = stats + (blockIdx.x & 7) * 256;
        atomicAdd(&sh[c], a1);
        atomicAdd(&sh[c + 1], b1);
        atomicAdd(&sh[128 + c], a2);
        atomicAdd(&sh[128 + c + 1], b2);
    }
}

extern "C" void kernel_launch(void* const* d_in, const int* in_sizes, int n_in,
                              void* d_out, int out_size, void* d_ws, size_t ws_size,
                              hipStream_t stream) {
    (void)n_in; (void)out_size; (void)ws_size;
    const float* x    = (const float*)d_in[0];
    const float* Win  = (const float*)d_in[1];
    const float* bin  = (const float*)d_in[2];
    const float* Wg   = (const float*)d_in[3];
    // d_in[4] = b_g: cancelled by BN mean-subtract, unused.
    const float* gamma = (const float*)d_in[5];
    const float* beta  = (const float*)d_in[6];
    const float* Wout  = (const float*)d_in[7];
    const float* bout  = (const float*)d_in[8];
    const int*   eidx  = (const int*)d_in[9];
    float* out = (float*)d_out;

    const int N = in_sizes[0] / 128;   // 50000 nodes
    const int E = in_sizes[9] / 2;     // 600000 edges
    const int* esrc_in = eidx;
    const int* edst_in = eidx + E;

    char* p = (char*)d_ws;
    auto alloc = [&](size_t bytes) { char* r = p; p += (bytes + 255) & ~(size_t)255; return r; };
    const size_t NB2 = (size_t)N * 128 * sizeof(unsigned short);
    unsigned short* h0b   = (unsigned short*)alloc(NB2);  // x_skip (bf16)
    unsigned short* tb16  = (unsigned short*)alloc(NB2);  // t (bf16)
    unsigned short* aggb  = (unsigned short*)alloc(NB2);  // agg (bf16)
    unsigned short* accb  = (unsigned short*)alloc(NB2);  // ACC (bf16)
    unsigned short* WinT  = (unsigned short*)alloc(128 * 128 * 2);
    unsigned short* WgT   = (unsigned short*)alloc(4 * 128 * 128 * 2);
    unsigned short* WoutT = (unsigned short*)alloc(128 * 64 * 2);
    float* disb  = (float*)alloc((size_t)N * 4);
    float* selfn = (float*)alloc((size_t)N * 4);
    // ---- contiguous zero region: cnt | bsum | boff | done | stats4 ----
    char* z0 = p;
    int*      cnt    = (int*)alloc((size_t)N * 4);
    unsigned* bsum   = (unsigned*)alloc(256 * 4);
    unsigned* boff   = (unsigned*)alloc(256 * 4);
    unsigned* done   = (unsigned*)alloc(256);
    float*    stats4 = (float*)alloc((size_t)4 * 8 * 256 * 4);   // [layer][shard 0..7][256]
    const size_t zbytes = (size_t)(p - z0);
    int*   rowptr = (int*)alloc((size_t)(N + 1) * 4);
    int*   cursor = (int*)alloc((size_t)N * 4);
    unsigned long long* epack = (unsigned long long*)alloc((size_t)E * 8);

    auto cdiv = [](int a, int b) { return (a + b - 1) / b; };
    const int NBLK = cdiv(N, 256);     // 196 (must be <= 256 for scanall)
    const float inv_n = 1.0f / (float)N;
    const int AGG_BLOCKS = 2048;       // 8192 waves = full residency; ~6 nodes/wave
    const int AGG_WAVES  = AGG_BLOCKS * 4;
    const int GB = cdiv(N, 64);        // mgemm2 tile blocks (782)
    const int FB = 8 * cdiv(E, 256);   // fill blocks: 8 ranges x edge windows (18752)

    // graph preprocessing (+ weight transposes fused into the hist launch)
    hipMemsetAsync(z0, 0, zbytes, stream);
    histw_kernel<<<cdiv(E, 256) + 352, 256, 0, stream>>>(edst_in, cnt, E,
                                                         Win, Wg, Wout, WinT, WgT, WoutT);
    scanall_kernel<<<NBLK, 256, 0, stream>>>(cnt, bsum, boff, done, rowptr, cursor,
                                             disb, selfn, N, NBLK);

    // merged: startup GEMMs (h0 = x@W_in+b_in ; t0 = h0@Wg[0]) || XCD-affine CSR fill
    fillgemm_kernel<<<GB + FB, 256, 0, stream>>>(x, WinT, bin, WgT, h0b, tb16, N, GB,
                                                 esrc_in, edst_in, cursor, disb, epack, E);

    for (int i = 0; i < 4; ++i) {
        float* stats = stats4 + (size_t)i * 8 * 256;
        aggstat_kernel<<<AGG_BLOCKS, 256, 0, stream>>>(tb16, rowptr, epack, selfn,
                                                       aggb, stats, N, AGG_WAVES);
        if (i < 3) {
            mgemm_bn_kernel<128, false, true><<<cdiv(N, 64), 256, 0, stream>>>(
                aggb, stats, gamma + i * 128, beta + i * 128, h0b, accb,
                WgT + (size_t)(i + 1) * 128 * 128, nullptr, (void*)tb16, N,
                inv_n, (i & 1), (i == 0) ? 1 : 0);
        } else {
            mgemm_bn_kernel<64, true, false><<<cdiv(N, 64), 256, 0, stream>>>(
                aggb, stats, gamma + i * 128, beta + i * 128, h0b, accb,
                WoutT, bout, (void*)out, N, inv_n, 1, 0);
        }
    }
}